// Round 17
// baseline (2870.512 us; speedup 1.0000x reference)
//
#include <hip/hip_runtime.h>
#include <hip/hip_bf16.h>
#include <math.h>
#include <stdint.h>

#define NN 6000
#define NE 96000
#define KDIN 3000
#define NCAND 12            // candidates per 128-col tile
#define NTILE 47
#define TCAND (NCAND*NTILE) // 564 per row
#define PRE 32              // f64-rescored candidates per row

// output element offsets (d_out is FLOAT32)
#define OFF_ZOUT 0
#define OFF_DE1  1536000
#define OFF_Q    19536000
#define OFF_FEAT 19596000
#define OFF_DE2  20364000
#define OFF_X1   38364000
#define OFF_ATT  52188000

typedef __attribute__((ext_vector_type(8))) short short8;
typedef __attribute__((ext_vector_type(4))) float f32x4;

__device__ __forceinline__ unsigned short f2bf(float f){
  unsigned int u = __float_as_uint(f);
  u += 0x7FFFu + ((u >> 16) & 1u);
  return (unsigned short)(u >> 16);
}
__device__ __forceinline__ float bf2f(unsigned short h){
  return __uint_as_float(((unsigned int)h) << 16);
}

// ---------------- weight prep: transpose, cast to f64 -----------------------
__global__ void prep_k(const float* __restrict__ W1, const float* __restrict__ W2,
                       const float* __restrict__ Wq, const float* __restrict__ Wk,
                       const float* __restrict__ Wv, const float* __restrict__ Ws,
                       const float* __restrict__ bq, const float* __restrict__ bk,
                       const float* __restrict__ bv, const float* __restrict__ bs,
                       const float* __restrict__ decW, const float* __restrict__ spat,
                       double* __restrict__ W1t, double* __restrict__ W2t,
                       double* __restrict__ Bct, float* __restrict__ Dt,
                       double* __restrict__ bcat,
                       double* __restrict__ sx64, double* __restrict__ sy64,
                       double* __restrict__ ssq64,
                       float* __restrict__ sx32, float* __restrict__ sy32)
{
  int t = blockIdx.x * 256 + threadIdx.x;
  if (t < 768000){
    int n = t / 3000, k = t % 3000;
    W1t[t] = (double)W1[(size_t)k * 256 + n]; return;
  }
  t -= 768000;
  if (t < 32768){
    int n = t / 256, k = t % 256;
    W2t[t] = (double)W2[(size_t)k * 128 + n]; return;
  }
  t -= 32768;
  if (t < 196608){
    int l = t / 65536; int rem = t % 65536;
    int n = rem / 128, k = rem % 128;
    int sel = n >> 7, nn = n & 127;
    const float* Wm = sel==0 ? Wq : sel==1 ? Wk : sel==2 ? Wv : Ws;
    Bct[t] = (double)Wm[((size_t)(l*128) + k) * 128 + nn]; return;
  }
  t -= 196608;
  if (t < 768000){
    int n = t / 256, k = t % 256;
    Dt[t] = decW[(size_t)k * 3000 + n]; return;
  }
  t -= 768000;
  if (t < 1536){
    int l = t / 512, n = t % 512;
    int sel = n >> 7, nn = n & 127;
    const float* bm = sel==0 ? bq : sel==1 ? bk : sel==2 ? bv : bs;
    bcat[t] = (double)bm[l*128 + nn]; return;
  }
  t -= 1536;
  if (t < NN){
    float sx = spat[(size_t)t*2], sy = spat[(size_t)t*2+1];
    sx64[t]=(double)sx; sy64[t]=(double)sy;
    ssq64[t]=(double)sx*(double)sx + (double)sy*(double)sy;
    sx32[t]=sx; sy32[t]=sy; return;
  }
}

__global__ void castup_k(const float* __restrict__ s, double* __restrict__ d, int n){
  int t = blockIdx.x*256 + threadIdx.x;
  if (t < n) d[t] = (double)s[t];
}

// split f64 z -> bf16 hi/lo (via f32)
__global__ void splitz_k(const double* __restrict__ z64, unsigned short* __restrict__ zh,
                         unsigned short* __restrict__ zl, int n){
  int t = blockIdx.x*256 + threadIdx.x;
  if (t < n){
    float v = (float)z64[t];
    unsigned short h = f2bf(v);
    float r = v - bf2f(h);
    zh[t] = h; zl[t] = f2bf(r);
  }
}

// ---------------- f64 vector GEMM, NT, 64x64, double2 LDS reads -------------
template<int EPI, typename TA>
__global__ __launch_bounds__(256)
void gemm64_k(const TA* __restrict__ A, int lda,
              const double* __restrict__ Bt, int ldb,
              int M, int K, int Ncol,
              double* __restrict__ outF, int ldc,
              const double* __restrict__ bias,
              const float* __restrict__ gam, const float* __restrict__ bet,
              double* __restrict__ outF2)
{
  __shared__ double lA[64][34];
  __shared__ double lB[64][34];
  const int tid = threadIdx.x;
  const int m0 = blockIdx.y * 64;
  const int n0 = blockIdx.x * 64;
  const int tx = tid & 15;
  const int ty = tid >> 4;

  double acc[4][4];
  #pragma unroll
  for (int i=0;i<4;i++)
    #pragma unroll
    for (int j=0;j<4;j++) acc[i][j] = 0.0;

  const int nkt = (K + 31) >> 5;
  for (int kt = 0; kt < nkt; kt++){
    const int k0 = kt << 5;
    __syncthreads();
    #pragma unroll
    for (int c=0;c<8;c++){
      int lin = tid + c*256;
      int row = lin >> 5, col = lin & 31;
      int gm = m0 + row, gk = k0 + col;
      double va = 0.0, vb = 0.0;
      if (gm < M && gk < K)        va = (double)A [(size_t)gm*lda + gk];
      if (n0+row < Ncol && gk < K) vb = Bt[(size_t)(n0+row)*ldb + gk];
      lA[row][col] = va;
      lB[row][col] = vb;
    }
    __syncthreads();
    #pragma unroll 4
    for (int kk=0; kk<32; kk+=2){
      double2 A0 = *(const double2*)&lA[ty   ][kk];
      double2 A1 = *(const double2*)&lA[ty+16][kk];
      double2 A2 = *(const double2*)&lA[ty+32][kk];
      double2 A3 = *(const double2*)&lA[ty+48][kk];
      double2 B0 = *(const double2*)&lB[tx   ][kk];
      double2 B1 = *(const double2*)&lB[tx+16][kk];
      double2 B2 = *(const double2*)&lB[tx+32][kk];
      double2 B3 = *(const double2*)&lB[tx+48][kk];
      acc[0][0]+=A0.x*B0.x; acc[0][1]+=A0.x*B1.x; acc[0][2]+=A0.x*B2.x; acc[0][3]+=A0.x*B3.x;
      acc[1][0]+=A1.x*B0.x; acc[1][1]+=A1.x*B1.x; acc[1][2]+=A1.x*B2.x; acc[1][3]+=A1.x*B3.x;
      acc[2][0]+=A2.x*B0.x; acc[2][1]+=A2.x*B1.x; acc[2][2]+=A2.x*B2.x; acc[2][3]+=A2.x*B3.x;
      acc[3][0]+=A3.x*B0.x; acc[3][1]+=A3.x*B1.x; acc[3][2]+=A3.x*B2.x; acc[3][3]+=A3.x*B3.x;
      acc[0][0]+=A0.y*B0.y; acc[0][1]+=A0.y*B1.y; acc[0][2]+=A0.y*B2.y; acc[0][3]+=A0.y*B3.y;
      acc[1][0]+=A1.y*B0.y; acc[1][1]+=A1.y*B1.y; acc[1][2]+=A1.y*B2.y; acc[1][3]+=A1.y*B3.y;
      acc[2][0]+=A2.y*B0.y; acc[2][1]+=A2.y*B1.y; acc[2][2]+=A2.y*B2.y; acc[2][3]+=A2.y*B3.y;
      acc[3][0]+=A3.y*B0.y; acc[3][1]+=A3.y*B1.y; acc[3][2]+=A3.y*B2.y; acc[3][3]+=A3.y*B3.y;
    }
  }
  #pragma unroll
  for (int j=0;j<4;j++){
    int gn = n0 + tx + 16*j;
    if (gn >= Ncol) continue;
    double bi = bias[gn];
    #pragma unroll
    for (int i=0;i<4;i++){
      int gm = m0 + ty + 16*i;
      if (gm >= M) continue;
      double v = acc[i][j] + bi;
      outF[(size_t)gm*ldc + gn] = v;
      if (outF2) outF2[(size_t)gm*ldc + gn] = v;
    }
  }
}

// ---------------- split-K f64 GEMM: partial per blockIdx.z ------------------
template<typename TA>
__global__ __launch_bounds__(256)
void gemm64s_k(const TA* __restrict__ A, int lda,
               const double* __restrict__ Bt, int ldb,
               int M, int K, int kchunk, int Ncol,
               double* __restrict__ part)   // [z][M*Ncol]
{
  __shared__ double lA[64][34];
  __shared__ double lB[64][34];
  const int tid = threadIdx.x;
  const int m0 = blockIdx.y * 64;
  const int n0 = blockIdx.x * 64;
  const int tx = tid & 15;
  const int ty = tid >> 4;
  const int kbeg = blockIdx.z * kchunk;
  const int kend = min(K, kbeg + kchunk);
  double* dst = part + (size_t)blockIdx.z * M * Ncol;

  double acc[4][4];
  #pragma unroll
  for (int i=0;i<4;i++)
    #pragma unroll
    for (int j=0;j<4;j++) acc[i][j] = 0.0;

  const int nkt = (kend - kbeg + 31) >> 5;
  for (int kt = 0; kt < nkt; kt++){
    const int k0 = kbeg + (kt << 5);
    __syncthreads();
    #pragma unroll
    for (int c=0;c<8;c++){
      int lin = tid + c*256;
      int row = lin >> 5, col = lin & 31;
      int gm = m0 + row, gk = k0 + col;
      double va = 0.0, vb = 0.0;
      if (gm < M && gk < kend)        va = (double)A [(size_t)gm*lda + gk];
      if (n0+row < Ncol && gk < kend) vb = Bt[(size_t)(n0+row)*ldb + gk];
      lA[row][col] = va;
      lB[row][col] = vb;
    }
    __syncthreads();
    #pragma unroll 4
    for (int kk=0; kk<32; kk+=2){
      double2 A0 = *(const double2*)&lA[ty   ][kk];
      double2 A1 = *(const double2*)&lA[ty+16][kk];
      double2 A2 = *(const double2*)&lA[ty+32][kk];
      double2 A3 = *(const double2*)&lA[ty+48][kk];
      double2 B0 = *(const double2*)&lB[tx   ][kk];
      double2 B1 = *(const double2*)&lB[tx+16][kk];
      double2 B2 = *(const double2*)&lB[tx+32][kk];
      double2 B3 = *(const double2*)&lB[tx+48][kk];
      acc[0][0]+=A0.x*B0.x; acc[0][1]+=A0.x*B1.x; acc[0][2]+=A0.x*B2.x; acc[0][3]+=A0.x*B3.x;
      acc[1][0]+=A1.x*B0.x; acc[1][1]+=A1.x*B1.x; acc[1][2]+=A1.x*B2.x; acc[1][3]+=A1.x*B3.x;
      acc[2][0]+=A2.x*B0.x; acc[2][1]+=A2.x*B1.x; acc[2][2]+=A2.x*B2.x; acc[2][3]+=A2.x*B3.x;
      acc[3][0]+=A3.x*B0.x; acc[3][1]+=A3.x*B1.x; acc[3][2]+=A3.x*B2.x; acc[3][3]+=A3.x*B3.x;
      acc[0][0]+=A0.y*B0.y; acc[0][1]+=A0.y*B1.y; acc[0][2]+=A0.y*B2.y; acc[0][3]+=A0.y*B3.y;
      acc[1][0]+=A1.y*B0.y; acc[1][1]+=A1.y*B1.y; acc[1][2]+=A1.y*B2.y; acc[1][3]+=A1.y*B3.y;
      acc[2][0]+=A2.y*B0.y; acc[2][1]+=A2.y*B1.y; acc[2][2]+=A2.y*B2.y; acc[2][3]+=A2.y*B3.y;
      acc[3][0]+=A3.y*B0.y; acc[3][1]+=A3.y*B1.y; acc[3][2]+=A3.y*B2.y; acc[3][3]+=A3.y*B3.y;
    }
  }
  #pragma unroll
  for (int j=0;j<4;j++){
    int gn = n0 + tx + 16*j;
    if (gn >= Ncol) continue;
    #pragma unroll
    for (int i=0;i<4;i++){
      int gm = m0 + ty + 16*i;
      if (gm >= M) continue;
      dst[(size_t)gm*Ncol + gn] = acc[i][j];
    }
  }
}

// reduce partials + bias + BN + ELU -> out (f64)
__global__ void epi64_k(const double* __restrict__ part, int nsplit, size_t pstride,
                        int M, int Ncol, const double* __restrict__ bias,
                        const float* __restrict__ gam, const float* __restrict__ bet,
                        double* __restrict__ out, int ldo)
{
  int t = blockIdx.x*256 + threadIdx.x;
  if (t >= M*Ncol) return;
  int gm = t / Ncol, gn = t - gm*Ncol;
  double v = 0.0;
  for (int s=0; s<nsplit; s++) v += part[(size_t)s*pstride + t];
  const double BNS = 0.99995000374968755261;
  v += bias[gn];
  v = v * ((double)gam[gn]*BNS) + (double)bet[gn];
  v = v > 0.0 ? v : expm1(v);
  out[(size_t)gm*ldo + gn] = v;
}

// ---------------- f32 GEMM (decoder, elu-bn to two f32 outs) ----------------
__global__ __launch_bounds__(256)
void gemm32d_k(const float* __restrict__ A, int lda,
               const float* __restrict__ Bt, int ldb,
               int M, int K, int Ncol,
               float* __restrict__ out1, int ldc,
               const float* __restrict__ bias, const float* __restrict__ gam,
               const float* __restrict__ bet, float* __restrict__ out2)
{
  __shared__ float lA[64][33];
  __shared__ float lB[64][33];
  const int tid = threadIdx.x;
  const int m0 = blockIdx.y * 64;
  const int n0 = blockIdx.x * 64;
  const int tx = tid & 15;
  const int ty = tid >> 4;

  float acc[4][4];
  #pragma unroll
  for (int i=0;i<4;i++)
    #pragma unroll
    for (int j=0;j<4;j++) acc[i][j] = 0.f;

  const int nkt = (K + 31) >> 5;
  for (int kt = 0; kt < nkt; kt++){
    const int k0 = kt << 5;
    __syncthreads();
    #pragma unroll
    for (int c=0;c<8;c++){
      int lin = tid + c*256;
      int row = lin >> 5, col = lin & 31;
      int gm = m0 + row, gk = k0 + col;
      float va = 0.f, vb = 0.f;
      if (gm < M && gk < K)        va = A [(size_t)gm*lda + gk];
      if (n0+row < Ncol && gk < K) vb = Bt[(size_t)(n0+row)*ldb + gk];
      lA[row][col] = va;
      lB[row][col] = vb;
    }
    __syncthreads();
    #pragma unroll 4
    for (int kk=0; kk<32; kk++){
      float a0=lA[ty][kk], a1=lA[ty+16][kk], a2=lA[ty+32][kk], a3=lA[ty+48][kk];
      float b0=lB[tx][kk], b1=lB[tx+16][kk], b2=lB[tx+32][kk], b3=lB[tx+48][kk];
      acc[0][0]+=a0*b0; acc[0][1]+=a0*b1; acc[0][2]+=a0*b2; acc[0][3]+=a0*b3;
      acc[1][0]+=a1*b0; acc[1][1]+=a1*b1; acc[1][2]+=a1*b2; acc[1][3]+=a1*b3;
      acc[2][0]+=a2*b0; acc[2][1]+=a2*b1; acc[2][2]+=a2*b2; acc[2][3]+=a2*b3;
      acc[3][0]+=a3*b0; acc[3][1]+=a3*b1; acc[3][2]+=a3*b2; acc[3][3]+=a3*b3;
    }
  }
  const float BNS = 0.99995000374968755f;
  #pragma unroll
  for (int j=0;j<4;j++){
    int gn = n0 + tx + 16*j;
    if (gn >= Ncol) continue;
    float bi = bias[gn];
    float gs = gam[gn]*BNS, be = bet[gn];
    #pragma unroll
    for (int i=0;i<4;i++){
      int gm = m0 + ty + 16*i;
      if (gm >= M) continue;
      float v = acc[i][j] + bi;
      v = v*gs + be; v = v > 0.f ? v : expm1f(v);
      out1[(size_t)gm*ldc + gn] = v;
      out2[(size_t)gm*ldc + gn] = v;
    }
  }
}

// ---------------- CSR build --------------------------------------------------
__global__ void csr_cnt_k(const int* __restrict__ key, int* __restrict__ cnt){
  int e = blockIdx.x*256 + threadIdx.x;
  if (e < NE) atomicAdd(&cnt[key[e]], 1);
}
__global__ __launch_bounds__(256)
void csr_scan_k(const int* __restrict__ cnt, int* __restrict__ rowptr, int* __restrict__ cursor){
  __shared__ int part[256];
  int t = threadIdx.x;
  int base = t*24;
  int loc[24]; int s=0;
  #pragma unroll
  for (int u=0;u<24;u++){
    int idx = base+u;
    int v = (idx<NN) ? cnt[idx] : 0;
    loc[u] = s; s += v;
  }
  part[t] = s;
  __syncthreads();
  if (t==0){
    int run=0;
    for (int u=0;u<256;u++){ int tmp=part[u]; part[u]=run; run+=tmp; }
  }
  __syncthreads();
  int off = part[t];
  #pragma unroll
  for (int u=0;u<24;u++){
    int idx = base+u;
    if (idx<NN){ rowptr[idx]=off+loc[u]; cursor[idx]=off+loc[u]; }
  }
  if (t==255) rowptr[NN] = off + s;
}
__global__ void csr_fill_k(const int* __restrict__ key, int* __restrict__ cursor,
                           int* __restrict__ elist){
  int e = blockIdx.x*256 + threadIdx.x;
  if (e < NE){ int pos = atomicAdd(&cursor[key[e]], 1); elist[pos] = e; }
}

// ---------------- fused per-node attention (dst-CSR, no atomics) ------------
__global__ __launch_bounds__(256)
void attn_k(double* __restrict__ QKVS, const int* __restrict__ rowptr,
            const int* __restrict__ elist, const int* __restrict__ src,
            double* __restrict__ alpha)
{
  __shared__ double lg[4][128];
  const int w = threadIdx.x >> 6;
  const int node = blockIdx.x*4 + w;
  if (node >= NN) return;
  const int lane = threadIdx.x & 63;
  const int e0 = rowptr[node], e1 = rowptr[node+1];
  const int deg = e1 - e0;
  if (deg <= 0) return;
  const double SC = 0.088388347648318447; // 1/sqrt(128)
  const double* q = QKVS + (size_t)node*512;
  double q0 = q[lane], q1 = q[lane+64];

  if (deg <= 128){
    double m = -1.0e300;
    for (int i=0;i<deg;i++){
      const double* k = QKVS + (size_t)src[elist[e0+i]]*512 + 128;
      double p = q0*k[lane] + q1*k[lane+64];
      #pragma unroll
      for (int off=32; off; off>>=1) p += __shfl_xor(p, off);
      p *= SC;
      if (lane==0) lg[w][i] = p;
      m = fmax(m, p);
    }
    double S = 0.0;
    for (int i=0;i<deg;i++){
      double ex = exp(lg[w][i] - m);
      if (lane==0) lg[w][i] = ex;
      S += ex;
    }
    double inv = 1.0 / S;
    double o0 = QKVS[(size_t)node*512 + 384 + lane];
    double o1 = QKVS[(size_t)node*512 + 448 + lane];
    for (int i=0;i<deg;i++){
      int e = elist[e0+i];
      double a = lg[w][i] * inv;
      const double* v = QKVS + (size_t)src[e]*512 + 256;
      o0 = fma(a, v[lane],    o0);
      o1 = fma(a, v[lane+64], o1);
      if (lane==0) alpha[e] = a;
    }
    QKVS[(size_t)node*512 + 384 + lane] = o0;
    QKVS[(size_t)node*512 + 448 + lane] = o1;
  } else {
    double m = -1.0e300;
    for (int i=0;i<deg;i++){
      const double* k = QKVS + (size_t)src[elist[e0+i]]*512 + 128;
      double p = q0*k[lane] + q1*k[lane+64];
      #pragma unroll
      for (int off=32; off; off>>=1) p += __shfl_xor(p, off);
      m = fmax(m, p*SC);
    }
    double S = 0.0;
    for (int i=0;i<deg;i++){
      const double* k = QKVS + (size_t)src[elist[e0+i]]*512 + 128;
      double p = q0*k[lane] + q1*k[lane+64];
      #pragma unroll
      for (int off=32; off; off>>=1) p += __shfl_xor(p, off);
      S += exp(p*SC - m);
    }
    double inv = 1.0 / S;
    double o0 = QKVS[(size_t)node*512 + 384 + lane];
    double o1 = QKVS[(size_t)node*512 + 448 + lane];
    for (int i=0;i<deg;i++){
      int e = elist[e0+i];
      const double* k = QKVS + (size_t)src[e]*512 + 128;
      double p = q0*k[lane] + q1*k[lane+64];
      #pragma unroll
      for (int off=32; off; off>>=1) p += __shfl_xor(p, off);
      double a = exp(p*SC - m) * inv;
      const double* v = QKVS + (size_t)src[e]*512 + 256;
      o0 = fma(a, v[lane],    o0);
      o1 = fma(a, v[lane+64], o1);
      if (lane==0) alpha[e] = a;
    }
    QKVS[(size_t)node*512 + 384 + lane] = o0;
    QKVS[(size_t)node*512 + 448 + lane] = o1;
  }
}

// ---------------- fused spmm over src-CSR (both graphs, no atomics) ---------
__global__ __launch_bounds__(256)
void spmm_csr_k(const double* __restrict__ QK1, const double* __restrict__ QK2,
                const int* __restrict__ rpSA, const int* __restrict__ elSA,
                const int* __restrict__ dstA, const double* __restrict__ aA,
                const int* __restrict__ rpSP, const int* __restrict__ elSP,
                const int* __restrict__ dstP, const double* __restrict__ aP,
                double* __restrict__ out, int ldo, int offo, int dorelu)
{
  const int node = blockIdx.x*4 + (threadIdx.x>>6);
  if (node >= NN) return;
  const int lane = threadIdx.x & 63;
  double a0 = 0.0, a1 = 0.0;
  for (int idx = rpSA[node]; idx < rpSA[node+1]; ++idx){
    int e = elSA[idx]; int d = dstA[e];
    if (d != node){
      double wgt = 0.5 * aA[e];
      const double* o = QK1 + (size_t)d*512 + 384;
      a0 = fma(wgt, o[lane],    a0);
      a1 = fma(wgt, o[lane+64], a1);
    }
  }
  for (int idx = rpSP[node]; idx < rpSP[node+1]; ++idx){
    int e = elSP[idx]; int d = dstP[e];
    if (d != node){
      double wgt = 0.5 * aP[e];
      const double* o = QK2 + (size_t)d*512 + 384;
      a0 = fma(wgt, o[lane],    a0);
      a1 = fma(wgt, o[lane+64], a1);
    }
  }
  if (dorelu){ a0 = fmax(a0, 0.0); a1 = fmax(a1, 0.0); }
  out[(size_t)node*ldo + offo + lane]      = a0;
  out[(size_t)node*ldo + offo + 64 + lane] = a1;
}

__global__ void att_scatter_k(const int* __restrict__ src, const int* __restrict__ dst,
                              const double* __restrict__ alpha, float* __restrict__ att)
{
  int e = blockIdx.x*256 + threadIdx.x;
  if (e >= NE) return;
  int s = src[e], d = dst[e];
  if (s == d) return;
  atomicAdd(&att[(size_t)s*NN + d], (float)alpha[e]);
}

// ---------------- MFMA bf16 2-split distance + fused per-tile top-12 --------
__global__ __launch_bounds__(256)
void distmf_k(const unsigned short* __restrict__ zXh, const unsigned short* __restrict__ zXl,
              const unsigned short* __restrict__ zNh, const unsigned short* __restrict__ zNl,
              const float* __restrict__ sxA, const float* __restrict__ syA,
              const float* __restrict__ cjA,
              float* __restrict__ candV, int* __restrict__ candI)
{
  __shared__ __align__(16) char smem[40960 + 1536];
  typedef unsigned short u16;
  u16 (*lAh)[40] = (u16(*)[40])(smem);
  u16 (*lAl)[40] = (u16(*)[40])(smem + 10240);
  u16 (*lBh)[40] = (u16(*)[40])(smem + 20480);
  u16 (*lBl)[40] = (u16(*)[40])(smem + 30720);
  float (*stile)[67] = (float(*)[67])(smem);     // overlay after K loop
  float* sSx = (float*)(smem + 40960);
  float* sSy = sSx + 128;
  float* sC  = sSy + 128;

  const int tid = threadIdx.x;
  const int m0 = blockIdx.y * 128;
  const int n0 = blockIdx.x * 128;
  const int lane = tid & 63;
  const int wave = tid >> 6;
  const int wm = wave >> 1, wn = wave & 1;
  const int lr = lane & 15;
  const int lk = (lane >> 4) * 8;

  if (tid < 128){
    int jg = n0 + tid;
    if (jg < NN){ sSx[tid]=sxA[jg]; sSy[tid]=syA[jg]; sC[tid]=cjA[jg]; }
    else        { sSx[tid]=0.f; sSy[tid]=0.f; sC[tid]=-3e38f; }
  }

  f32x4 acc[4][4];
  #pragma unroll
  for (int i=0;i<4;i++)
    #pragma unroll
    for (int j=0;j<4;j++) acc[i][j] = (f32x4){0.f,0.f,0.f,0.f};

  for (int kt = 0; kt < 8; kt++){
    const int k0 = kt << 5;
    __syncthreads();
    #pragma unroll
    for (int c=0;c<4;c++){
      int lin = tid + c*256;
      int row = lin >> 3;
      int kc = (lin & 7) << 2;
      int gm = m0 + row, gn = n0 + row;
      ushort4 vh = {0,0,0,0}, vl = {0,0,0,0}, wh = {0,0,0,0}, wl = {0,0,0,0};
      if (gm < NN){
        vh = *(const ushort4*)(zXh + (size_t)gm*256 + k0 + kc);
        vl = *(const ushort4*)(zXl + (size_t)gm*256 + k0 + kc);
      }
      if (gn < NN){
        wh = *(const ushort4*)(zNh + (size_t)gn*256 + k0 + kc);
        wl = *(const ushort4*)(zNl + (size_t)gn*256 + k0 + kc);
      }
      *(ushort4*)&lAh[row][kc] = vh;
      *(ushort4*)&lAl[row][kc] = vl;
      *(ushort4*)&lBh[row][kc] = wh;
      *(ushort4*)&lBl[row][kc] = wl;
    }
    __syncthreads();
    short8 ah[4], al[4];
    #pragma unroll
    for (int fm=0; fm<4; fm++){
      ah[fm] = *(const short8*)&lAh[wm*64 + fm*16 + lr][lk];
      al[fm] = *(const short8*)&lAl[wm*64 + fm*16 + lr][lk];
    }
    #pragma unroll
    for (int fn=0; fn<4; fn++){
      short8 bh = *(const short8*)&lBh[wn*64 + fn*16 + lr][lk];
      short8 bl = *(const short8*)&lBl[wn*64 + fn*16 + lr][lk];
      #pragma unroll
      for (int fm=0; fm<4; fm++){
        acc[fm][fn] = __builtin_amdgcn_mfma_f32_16x16x32_bf16(ah[fm], bh, acc[fm][fn], 0,0,0);
        acc[fm][fn] = __builtin_amdgcn_mfma_f32_16x16x32_bf16(ah[fm], bl, acc[fm][fn], 0,0,0);
        acc[fm][fn] = __builtin_amdgcn_mfma_f32_16x16x32_bf16(al[fm], bh, acc[fm][fn], 0,0,0);
      }
    }
  }

  float tv[NCAND]; int ti[NCAND];
  #pragma unroll
  for (int p=0;p<NCAND;p++){ tv[p] = -3.4e38f; ti[p] = -1; }
  const int gi = m0 + tid;
  float sxi = 0.f, syi = 0.f;
  if (tid < 128 && gi < NN){ sxi = sxA[gi]; syi = syA[gi]; }

  for (int jh = 0; jh < 2; jh++){
    __syncthreads();
    if (wn == jh){
      #pragma unroll
      for (int fm=0;fm<4;fm++){
        #pragma unroll
        for (int fn=0;fn<4;fn++){
          int lrow = wm*64 + fm*16 + ((lane>>4)<<2);
          int lcol = fn*16 + lr;
          #pragma unroll
          for (int r=0;r<4;r++)
            stile[lrow + r][lcol] = acc[fm][fn][r];
        }
      }
    }
    __syncthreads();
    if (tid < 128 && gi < NN){
      #pragma unroll 1
      for (int jj=0; jj<64; jj++){
        int j = jh*64 + jj;
        float s = 2.f*stile[tid][jj] + 2.f*(sxi*sSx[j] + syi*sSy[j]) + sC[j];
        if (s > tv[NCAND-1]){
          bool g[NCAND];
          #pragma unroll
          for (int p=0;p<NCAND;p++) g[p] = s > tv[p];
          #pragma unroll
          for (int p=NCAND-1;p>0;--p) if (g[p-1]){ tv[p]=tv[p-1]; ti[p]=ti[p-1]; }
          #pragma unroll
          for (int p=0;p<NCAND;p++){ bool pl = g[p] && (p==0 || !g[p-1]); if (pl){ tv[p]=s; ti[p]=n0+j; } }
        }
      }
    }
  }
  if (tid < 128 && gi < NN){
    size_t base = ((size_t)gi*NTILE + blockIdx.x)*NCAND;
    #pragma unroll
    for (int p=0;p<NCAND;p++){ candV[base+p]=tv[p]; candI[base+p]=ti[p]; }
  }
}

// ---------------- merge: 32x block-argmax prefilter -> f64 rescore -> top-9 -
__global__ __launch_bounds__(256)
void merge64_k(const float* __restrict__ candV, const int* __restrict__ candI,
               const double* __restrict__ Z, const double* __restrict__ Znb,
               const double* __restrict__ sx64, const double* __restrict__ sy64,
               double* __restrict__ wgt9, int* __restrict__ idx9)
{
  __shared__ double zi[256];
  __shared__ int    fjS[TCAND];
  __shared__ float  wbv[4];
  __shared__ int    wbc[4];
  __shared__ int    chosen;
  __shared__ int    pj[PRE];
  __shared__ double ps[PRE];

  const int i = blockIdx.x;
  const int t = threadIdx.x;
  const int lane = t & 63, wv = t >> 6;

  zi[t] = Z[(size_t)i*256 + t];

  float v0 = -3.4e38f, v1 = -3.4e38f, v2 = -3.4e38f;
  const int c0 = t, c1 = t + 256, c2 = t + 512;
  {
    float vv = candV[(size_t)i*TCAND + c0];
    int jj = candI[(size_t)i*TCAND + c0];
    fjS[c0] = jj;
    if (jj >= 0) v0 = vv;
  }
  if (c1 < TCAND){
    float vv = candV[(size_t)i*TCAND + c1];
    int jj = candI[(size_t)i*TCAND + c1];
    fjS[c1] = jj;
    if (jj >= 0) v1 = vv;
  }
  if (c2 < TCAND){
    float vv = candV[(size_t)i*TCAND + c2];
    int jj = candI[(size_t)i*TCAND + c2];
    fjS[c2] = jj;
    if (jj >= 0) v2 = vv;
  }
  __syncthreads();

  for (int it = 0; it < PRE; it++){
    float bv = v0; int bc = c0;
    if (v1 > bv || (v1 == bv && c1 < bc)){ bv = v1; bc = c1; }
    if (v2 > bv || (v2 == bv && c2 < bc)){ bv = v2; bc = c2; }
    #pragma unroll
    for (int off = 32; off; off >>= 1){
      float ov = __shfl_xor(bv, off);
      int   oc = __shfl_xor(bc, off);
      if (ov > bv || (ov == bv && oc < bc)){ bv = ov; bc = oc; }
    }
    if (lane == 0){ wbv[wv] = bv; wbc[wv] = bc; }
    __syncthreads();
    if (t == 0){
      float gb = wbv[0]; int gc = wbc[0];
      #pragma unroll
      for (int w2 = 1; w2 < 4; w2++)
        if (wbv[w2] > gb || (wbv[w2] == gb && wbc[w2] < gc)){ gb = wbv[w2]; gc = wbc[w2]; }
      chosen = gc;
      pj[it] = fjS[gc];
    }
    __syncthreads();
    int gc = chosen;
    if (c0 == gc) v0 = -3.4e38f;
    if (c1 == gc) v1 = -3.4e38f;
    if (c2 == gc) v2 = -3.4e38f;
  }

  const double sxi = sx64[i], syi = sy64[i];
  for (int c = wv; c < PRE; c += 4){
    int j = pj[c];
    const double* zj = Znb + (size_t)j*256;
    double p = 0.0;
    #pragma unroll
    for (int u = 0; u < 4; u++){
      double b = zj[lane + 64*u];
      double a = zi[lane + 64*u];
      p = fma(2.0*a - b, b, p);     // += 2ab - b^2
    }
    #pragma unroll
    for (int off = 32; off; off >>= 1) p += __shfl_xor(p, off);
    double sxj = sx64[j], syj = sy64[j];
    double s = p + 2.0*(sxi*sxj + syi*syj) - (sxj*sxj + syj*syj);
    if (lane == 0) ps[c] = s;
  }
  __syncthreads();

  if (t == 0){
    double tv9[9]; int ti9[9];
    #pragma unroll
    for (int p = 0; p < 9; p++){ tv9[p] = -1.0e301; ti9[p] = 0x7FFFFFFF; }
    for (int c = 0; c < PRE; c++){
      double s = ps[c]; int j = pj[c];
      if (!((s > tv9[8]) || (s == tv9[8] && j < ti9[8]))) continue;
      int p = 8;
      while (p > 0 && ((s > tv9[p-1]) || (s == tv9[p-1] && j < ti9[p-1]))){
        tv9[p] = tv9[p-1]; ti9[p] = ti9[p-1]; --p;
      }
      tv9[p] = s; ti9[p] = j;
    }
    double m = tv9[0], e[9], S = 0.0;
    #pragma unroll
    for (int k = 0; k < 9; k++){ e[k] = exp(tv9[k] - m); S += e[k]; }
    #pragma unroll
    for (int k = 0; k < 9; k++){
      wgt9[(size_t)i*9 + k] = e[k] / S;
      idx9[(size_t)i*9 + k] = ti9[k];
    }
  }
}

// ---------------- znb prep + casts ------------------------------------------
__global__ __launch_bounds__(256)
void znbprep_k(const double* __restrict__ znb, const double* __restrict__ ssq64,
               float* __restrict__ cjA)
{
  __shared__ double red[256];
  int i = blockIdx.x, d = threadIdx.x;
  double v = znb[(size_t)i*256 + d];
  red[d] = v*v;
  __syncthreads();
  for (int s=128; s; s>>=1){ if (d<s) red[d]+=red[d+s]; __syncthreads(); }
  if (d==0) cjA[i] = -(float)(red[0] + ssq64[i]);
}
__global__ void featout_k(const double* __restrict__ z, float* __restrict__ o){
  int t = blockIdx.x*256+threadIdx.x;
  if (t < NN*128){ int i=t>>7, d=t&127; o[t] = (float)z[(size_t)i*256 + d]; }
}

__global__ __launch_bounds__(256)
void zout_k(const double* __restrict__ Z, const double* __restrict__ Znb,
            const int* __restrict__ idx9, const double* __restrict__ wgt9,
            float* __restrict__ zoOut, float* __restrict__ zoF32, float* __restrict__ x1)
{
  int i = blockIdx.x; int d = threadIdx.x;
  double a = Z[(size_t)i*256 + d];
  #pragma unroll
  for (int k=0;k<9;k++){
    int j = idx9[(size_t)i*9+k];
    double w = wgt9[(size_t)i*9+k];
    double t = w * Znb[(size_t)j*256 + d];
    a += t;
    x1[((size_t)i*9+k)*256 + d] = (float)t;
  }
  float af = (float)a;
  zoOut[(size_t)i*256+d] = af;
  zoF32[(size_t)i*256+d] = af;
}

__global__ __launch_bounds__(256)
void q_k(const float* __restrict__ zoF, const float* __restrict__ clus, float* __restrict__ qB)
{
  __shared__ float wred[10][4];
  __shared__ float qs[10];
  int i = blockIdx.x, d = threadIdx.x;
  int lane = d & 63, wv = d >> 6;
  float zo = zoF[(size_t)i*256 + d];
  #pragma unroll
  for (int c=0;c<10;c++){
    float df = zo - clus[(size_t)c*256 + d];
    float p = df*df;
    #pragma unroll
    for (int off=32; off; off>>=1) p += __shfl_down(p, off);
    if (lane == 0) wred[c][wv] = p;
  }
  __syncthreads();
  if (d < 10){
    float d2 = wred[d][0]+wred[d][1]+wred[d][2]+wred[d][3];
    qs[d] = 1.f/(1.f + d2);
  }
  __syncthreads();
  if (d < 10){
    float s = 0.f;
    #pragma unroll
    for (int c=0;c<10;c++) s += qs[c];
    qB[(size_t)i*10 + d] = qs[d]/s;
  }
}

// ---------------- host ------------------------------------------------------
extern "C" void kernel_launch(void* const* d_in, const int* in_sizes, int n_in,
                              void* d_out, int out_size, void* d_ws, size_t ws_size,
                              hipStream_t stream)
{
  (void)in_sizes; (void)n_in; (void)out_size; (void)ws_size;
  const float* x    = (const float*)d_in[0];
  const float* xnb  = (const float*)d_in[1];
  const float* spat = (const float*)d_in[2];
  const int*   adj  = (const int*)d_in[3];
  const int*   adjp = (const int*)d_in[4];
  const float* W1   = (const float*)d_in[5];
  const float* b1   = (const float*)d_in[6];
  const float* g1   = (const float*)d_in[7];
  const float* be1  = (const float*)d_in[8];
  const float* W2   = (const float*)d_in[9];
  const float* b2   = (const float*)d_in[10];
  const float* g2   = (const float*)d_in[11];
  const float* be2  = (const float*)d_in[12];
  const float* Wq   = (const float*)d_in[13];
  const float* Wk   = (const float*)d_in[14];
  const float* Wv   = (const float*)d_in[15];
  const float* Wsm  = (const float*)d_in[16];
  const float* bq   = (const float*)d_in[17];
  const float* bk   = (const float*)d_in[18];
  const float* bv   = (const float*)d_in[19];
  const float* bs   = (const float*)d_in[20];
  const float* decW = (const float*)d_in[21];
  const float* decb = (const float*)d_in[22];
  const float* decg = (const float*)d_in[23];
  const float* decbe= (const float*)d_in[24];
  const float* clus = (const float*)d_in[25];
  float* outF = (float*)d_out;
  const int* srcA = adj,  *dstA = adj + NE;
  const int* srcP = adjp, *dstP = adjp + NE;

  char* wsb = (char*)d_ws;
  size_t off = 0;
  auto alloc = [&](size_t bytes)->char*{
    char* p = wsb + off;
    off = (off + bytes + 255) & ~(size_t)255;
    return p;
  };
  double* W1t  = (double*)alloc(768000*8);
  double* W2t  = (double*)alloc(32768*8);
  double* Bct  = (double*)alloc(196608*8);
  float*  Dt   = (float*) alloc(768000*4);
  double* bcat = (double*)alloc(1536*8);
  double* sx64 = (double*)alloc(NN*8);
  double* sy64 = (double*)alloc(NN*8);
  double* ssq64= (double*)alloc(NN*8);
  float*  sx32 = (float*) alloc(NN*4);
  float*  sy32 = (float*) alloc(NN*4);
  double* b1c  = (double*)alloc(256*8);
  double* b2c  = (double*)alloc(128*8);
  double* H1   = (double*)alloc((size_t)NN*256*8);
  double* zX64 = (double*)alloc((size_t)NN*256*8);
  double* zNB64= (double*)alloc((size_t)NN*256*8);
  double* hcur = (double*)alloc((size_t)NN*128*8);
  double* QK1  = (double*)alloc((size_t)NN*512*8);
  double* QK2  = (double*)alloc((size_t)NN*512*8);
  double* alphaA=(double*)alloc((size_t)NE*8);
  double* alphaP=(double*)alloc((size_t)NE*8);
  double* part = (double*)alloc((size_t)4*NN*256*8);   // split-K partials (49 MB)
  // CSRs
  int* rpDA = (int*)alloc((NN+1)*4);
  int* rpDP = (int*)alloc((NN+1)*4);
  int* rpSA = (int*)alloc((NN+1)*4);
  int* rpSP = (int*)alloc((NN+1)*4);
  int* curDA= (int*)alloc(NN*4);
  int* curDP= (int*)alloc(NN*4);
  int* curSA= (int*)alloc(NN*4);
  int* curSP= (int*)alloc(NN*4);
  int* elDA = (int*)alloc(NE*4);
  int* elDP = (int*)alloc(NE*4);
  int* elSA = (int*)alloc(NE*4);
  int* elSP = (int*)alloc(NE*4);
  unsigned short* zXh = (unsigned short*)alloc((size_t)NN*256*2);
  unsigned short* zXl = (unsigned short*)alloc((size_t)NN*256*2);
  unsigned short* zNh = (unsigned short*)alloc((size_t)NN*256*2);
  unsigned short* zNl = (unsigned short*)alloc((size_t)NN*256*2);
  float*  cjA  = (float*) alloc(NN*4);
  float*  candV= (float*) alloc((size_t)NN*TCAND*4);
  int*    candI= (int*)   alloc((size_t)NN*TCAND*4);
  int*    idx9 = (int*)   alloc((size_t)NN*9*4);
  double* wgt9 = (double*)alloc((size_t)NN*9*8);
  float*  zoF32= (float*) alloc((size_t)NN*256*4);

  prep_k<<<6926, 256, 0, stream>>>(W1, W2, Wq, Wk, Wv, Wsm, bq, bk, bv, bs, decW, spat,
                                   W1t, W2t, Bct, Dt, bcat,
                                   sx64, sy64, ssq64, sx32, sy32);
  castup_k<<<1, 256, 0, stream>>>(b1, b1c, 256);
  castup_k<<<1, 256, 0, stream>>>(b2, b2c, 128);

  // CSR build (4 CSRs)
  hipMemsetAsync(curDA, 0, NN*4, stream);
  hipMemsetAsync(curDP, 0, NN*4, stream);
  hipMemsetAsync(curSA, 0, NN*4, stream);
  hipMemsetAsync(curSP, 0, NN*4, stream);
  csr_cnt_k<<<375, 256, 0, stream>>>(dstA, curDA);
  csr_cnt_k<<<375, 256, 0, stream>>>(dstP, curDP);
  csr_cnt_k<<<375, 256, 0, stream>>>(srcA, curSA);
  csr_cnt_k<<<375, 256, 0, stream>>>(srcP, curSP);
  csr_scan_k<<<1, 256, 0, stream>>>(curDA, rpDA, curDA);
  csr_scan_k<<<1, 256, 0, stream>>>(curDP, rpDP, curDP);
  csr_scan_k<<<1, 256, 0, stream>>>(curSA, rpSA, curSA);
  csr_scan_k<<<1, 256, 0, stream>>>(curSP, rpSP, curSP);
  csr_fill_k<<<375, 256, 0, stream>>>(dstA, curDA, elDA);
  csr_fill_k<<<375, 256, 0, stream>>>(dstP, curDP, elDP);
  csr_fill_k<<<375, 256, 0, stream>>>(srcA, curSA, elSA);
  csr_fill_k<<<375, 256, 0, stream>>>(srcP, curSP, elSP);

  auto enc = [&](const float* xin, double* zbuf, bool isX){
    gemm64s_k<float><<<dim3(4,94,4), 256, 0, stream>>>(xin, KDIN, W1t, KDIN,
                                                       NN, KDIN, 768, 256, part);
    epi64_k<<<(NN*256+255)/256, 256, 0, stream>>>(part, 4, (size_t)NN*256,
                                                  NN, 256, b1c, g1, be1, H1, 256);
    gemm64s_k<double><<<dim3(2,94,4), 256, 0, stream>>>(H1, 256, W2t, 256,
                                                        NN, 256, 64, 128, part);
    epi64_k<<<(NN*128+255)/256, 256, 0, stream>>>(part, 4, (size_t)NN*128,
                                                  NN, 128, b2c, g2, be2, zbuf, 256);
    const double* hin = zbuf; int ldh = 256;
    for (int l=0; l<3; l++){
      const double* Bh = Bct + (size_t)l*65536;
      const double* bc = bcat + l*512;
      if (l != 1){
        gemm64_k<0,double><<<dim3(8,94), 256, 0, stream>>>(hin, ldh, Bh, 128, NN, 128, 512,
                                                           QK1, 512, bc, nullptr, nullptr, QK2);
        attn_k<<<1500, 256, 0, stream>>>(QK1, rpDA, elDA, srcA, alphaA);
        attn_k<<<1500, 256, 0, stream>>>(QK2, rpDP, elDP, srcP, alphaP);
      } else {
        gemm64_k<0,double><<<dim3(8,94), 256, 0, stream>>>(hin, ldh, Bh, 128, NN, 128, 512,
                                                           QK1, 512, bc, nullptr, nullptr, nullptr);
        attn_k<<<1500, 256, 0, stream>>>(QK1, rpDA, elDA, srcA, alphaA);
        gemm64_k<0,double><<<dim3(8,94), 256, 0, stream>>>(QK1 + 384, 512, Bh, 128, NN, 128, 512,
                                                           QK2, 512, bc, nullptr, nullptr, nullptr);
        attn_k<<<1500, 256, 0, stream>>>(QK2, rpDP, elDP, srcP, alphaP);
      }
      if (isX && l == 2){
        hipMemsetAsync(outF + (size_t)OFF_ATT, 0, (size_t)NN*NN*4, stream);
        att_scatter_k<<<375, 256, 0, stream>>>(srcP, dstP, alphaP, outF + (size_t)OFF_ATT);
      }
      if (l < 2){
        spmm_csr_k<<<1500, 256, 0, stream>>>(QK1, QK2, rpSA, elSA, dstA, alphaA,
                                             rpSP, elSP, dstP, alphaP, hcur, 128, 0, 1);
        hin = hcur; ldh = 128;
      } else {
        spmm_csr_k<<<1500, 256, 0, stream>>>(QK1, QK2, rpSA, elSA, dstA, alphaA,
                                             rpSP, elSP, dstP, alphaP, zbuf, 256, 128, 0);
      }
    }
  };
  enc(x,   zX64,  true);
  enc(xnb, zNB64, false);

  splitz_k<<<6000, 256, 0, stream>>>(zX64,  zXh, zXl, NN*256);
  splitz_k<<<6000, 256, 0, stream>>>(zNB64, zNh, zNl, NN*256);
  znbprep_k<<<NN, 256, 0, stream>>>(zNB64, ssq64, cjA);
  distmf_k<<<dim3(NTILE,47), 256, 0, stream>>>(zXh, zXl, zNh, zNl,
                                               sx32, sy32, cjA, candV, candI);
  merge64_k<<<NN, 256, 0, stream>>>(candV, candI, zX64, zNB64, sx64, sy64, wgt9, idx9);

  zout_k<<<NN, 256, 0, stream>>>(zX64, zNB64, idx9, wgt9,
                                 outF + (size_t)OFF_ZOUT, zoF32, outF + (size_t)OFF_X1);
  gemm32d_k<<<dim3(47,94), 256, 0, stream>>>(zoF32, 256, Dt, 256, NN, 256, 3000,
                                             outF + (size_t)OFF_DE1, 3000, decb, decg, decbe,
                                             outF + (size_t)OFF_DE2);
  q_k<<<NN, 256, 0, stream>>>(zoF32, clus, outF + (size_t)OFF_Q);
  featout_k<<<3000, 256, 0, stream>>>(zX64, outF + (size_t)OFF_FEAT);
}

// Round 18
// 2861.115 us; speedup vs baseline: 1.0033x; 1.0033x over previous
//
#include <hip/hip_runtime.h>
#include <hip/hip_bf16.h>
#include <math.h>
#include <stdint.h>

#define NN 6000
#define NE 96000
#define KDIN 3000
#define NCAND 12            // candidates per 128-col tile
#define NTILE 47
#define TCAND (NCAND*NTILE) // 564 per row
#define PRE 32              // f64-rescored candidates per row

// output element offsets (d_out is FLOAT32)
#define OFF_ZOUT 0
#define OFF_DE1  1536000
#define OFF_Q    19536000
#define OFF_FEAT 19596000
#define OFF_DE2  20364000
#define OFF_X1   38364000
#define OFF_ATT  52188000

typedef __attribute__((ext_vector_type(8))) short short8;
typedef __attribute__((ext_vector_type(4))) float f32x4;

__device__ __forceinline__ unsigned short f2bf(float f){
  unsigned int u = __float_as_uint(f);
  u += 0x7FFFu + ((u >> 16) & 1u);
  return (unsigned short)(u >> 16);
}
__device__ __forceinline__ float bf2f(unsigned short h){
  return __uint_as_float(((unsigned int)h) << 16);
}

// ---------------- weight prep: transpose, cast to f64 -----------------------
__global__ void prep_k(const float* __restrict__ W1, const float* __restrict__ W2,
                       const float* __restrict__ Wq, const float* __restrict__ Wk,
                       const float* __restrict__ Wv, const float* __restrict__ Ws,
                       const float* __restrict__ bq, const float* __restrict__ bk,
                       const float* __restrict__ bv, const float* __restrict__ bs,
                       const float* __restrict__ decW, const float* __restrict__ spat,
                       double* __restrict__ W1t, double* __restrict__ W2t,
                       double* __restrict__ Bct, float* __restrict__ Dt,
                       double* __restrict__ bcat,
                       double* __restrict__ sx64, double* __restrict__ sy64,
                       double* __restrict__ ssq64,
                       float* __restrict__ sx32, float* __restrict__ sy32)
{
  int t = blockIdx.x * 256 + threadIdx.x;
  if (t < 768000){
    int n = t / 3000, k = t % 3000;
    W1t[t] = (double)W1[(size_t)k * 256 + n]; return;
  }
  t -= 768000;
  if (t < 32768){
    int n = t / 256, k = t % 256;
    W2t[t] = (double)W2[(size_t)k * 128 + n]; return;
  }
  t -= 32768;
  if (t < 196608){
    int l = t / 65536; int rem = t % 65536;
    int n = rem / 128, k = rem % 128;
    int sel = n >> 7, nn = n & 127;
    const float* Wm = sel==0 ? Wq : sel==1 ? Wk : sel==2 ? Wv : Ws;
    Bct[t] = (double)Wm[((size_t)(l*128) + k) * 128 + nn]; return;
  }
  t -= 196608;
  if (t < 768000){
    int n = t / 256, k = t % 256;
    Dt[t] = decW[(size_t)k * 3000 + n]; return;
  }
  t -= 768000;
  if (t < 1536){
    int l = t / 512, n = t % 512;
    int sel = n >> 7, nn = n & 127;
    const float* bm = sel==0 ? bq : sel==1 ? bk : sel==2 ? bv : bs;
    bcat[t] = (double)bm[l*128 + nn]; return;
  }
  t -= 1536;
  if (t < NN){
    float sx = spat[(size_t)t*2], sy = spat[(size_t)t*2+1];
    sx64[t]=(double)sx; sy64[t]=(double)sy;
    ssq64[t]=(double)sx*(double)sx + (double)sy*(double)sy;
    sx32[t]=sx; sy32[t]=sy; return;
  }
}

__global__ void castup_k(const float* __restrict__ s, double* __restrict__ d, int n){
  int t = blockIdx.x*256 + threadIdx.x;
  if (t < n) d[t] = (double)s[t];
}

// split f64 z -> bf16 hi/lo (via f32)
__global__ void splitz_k(const double* __restrict__ z64, unsigned short* __restrict__ zh,
                         unsigned short* __restrict__ zl, int n){
  int t = blockIdx.x*256 + threadIdx.x;
  if (t < n){
    float v = (float)z64[t];
    unsigned short h = f2bf(v);
    float r = v - bf2f(h);
    zh[t] = h; zl[t] = f2bf(r);
  }
}

// ---------------- f64 vector GEMM, NT, 64x64, BK=16, double2 LDS reads ------
template<int EPI, typename TA>
__global__ __launch_bounds__(256)
void gemm64_k(const TA* __restrict__ A, int lda,
              const double* __restrict__ Bt, int ldb,
              int M, int K, int Ncol,
              double* __restrict__ outF, int ldc,
              const double* __restrict__ bias,
              const float* __restrict__ gam, const float* __restrict__ bet,
              double* __restrict__ outF2)
{
  __shared__ double lA[64][18];
  __shared__ double lB[64][18];
  const int tid = threadIdx.x;
  const int m0 = blockIdx.y * 64;
  const int n0 = blockIdx.x * 64;
  const int tx = tid & 15;
  const int ty = tid >> 4;

  double acc[4][4];
  #pragma unroll
  for (int i=0;i<4;i++)
    #pragma unroll
    for (int j=0;j<4;j++) acc[i][j] = 0.0;

  const int nkt = (K + 15) >> 4;
  for (int kt = 0; kt < nkt; kt++){
    const int k0 = kt << 4;
    __syncthreads();
    #pragma unroll
    for (int c=0;c<4;c++){
      int lin = tid + c*256;
      int row = lin >> 4, col = lin & 15;
      int gm = m0 + row, gk = k0 + col;
      double va = 0.0, vb = 0.0;
      if (gm < M && gk < K)        va = (double)A [(size_t)gm*lda + gk];
      if (n0+row < Ncol && gk < K) vb = Bt[(size_t)(n0+row)*ldb + gk];
      lA[row][col] = va;
      lB[row][col] = vb;
    }
    __syncthreads();
    #pragma unroll 4
    for (int kk=0; kk<16; kk+=2){
      double2 A0 = *(const double2*)&lA[ty   ][kk];
      double2 A1 = *(const double2*)&lA[ty+16][kk];
      double2 A2 = *(const double2*)&lA[ty+32][kk];
      double2 A3 = *(const double2*)&lA[ty+48][kk];
      double2 B0 = *(const double2*)&lB[tx   ][kk];
      double2 B1 = *(const double2*)&lB[tx+16][kk];
      double2 B2 = *(const double2*)&lB[tx+32][kk];
      double2 B3 = *(const double2*)&lB[tx+48][kk];
      acc[0][0]+=A0.x*B0.x; acc[0][1]+=A0.x*B1.x; acc[0][2]+=A0.x*B2.x; acc[0][3]+=A0.x*B3.x;
      acc[1][0]+=A1.x*B0.x; acc[1][1]+=A1.x*B1.x; acc[1][2]+=A1.x*B2.x; acc[1][3]+=A1.x*B3.x;
      acc[2][0]+=A2.x*B0.x; acc[2][1]+=A2.x*B1.x; acc[2][2]+=A2.x*B2.x; acc[2][3]+=A2.x*B3.x;
      acc[3][0]+=A3.x*B0.x; acc[3][1]+=A3.x*B1.x; acc[3][2]+=A3.x*B2.x; acc[3][3]+=A3.x*B3.x;
      acc[0][0]+=A0.y*B0.y; acc[0][1]+=A0.y*B1.y; acc[0][2]+=A0.y*B2.y; acc[0][3]+=A0.y*B3.y;
      acc[1][0]+=A1.y*B0.y; acc[1][1]+=A1.y*B1.y; acc[1][2]+=A1.y*B2.y; acc[1][3]+=A1.y*B3.y;
      acc[2][0]+=A2.y*B0.y; acc[2][1]+=A2.y*B1.y; acc[2][2]+=A2.y*B2.y; acc[2][3]+=A2.y*B3.y;
      acc[3][0]+=A3.y*B0.y; acc[3][1]+=A3.y*B1.y; acc[3][2]+=A3.y*B2.y; acc[3][3]+=A3.y*B3.y;
    }
  }
  #pragma unroll
  for (int j=0;j<4;j++){
    int gn = n0 + tx + 16*j;
    if (gn >= Ncol) continue;
    double bi = bias[gn];
    #pragma unroll
    for (int i=0;i<4;i++){
      int gm = m0 + ty + 16*i;
      if (gm >= M) continue;
      double v = acc[i][j] + bi;
      outF[(size_t)gm*ldc + gn] = v;
      if (outF2) outF2[(size_t)gm*ldc + gn] = v;
    }
  }
}

// ---------------- split-K f64 GEMM (BK=16): partial per blockIdx.z ----------
template<typename TA>
__global__ __launch_bounds__(256)
void gemm64s_k(const TA* __restrict__ A, int lda,
               const double* __restrict__ Bt, int ldb,
               int M, int K, int kchunk, int Ncol,
               double* __restrict__ part)   // [z][M*Ncol]
{
  __shared__ double lA[64][18];
  __shared__ double lB[64][18];
  const int tid = threadIdx.x;
  const int m0 = blockIdx.y * 64;
  const int n0 = blockIdx.x * 64;
  const int tx = tid & 15;
  const int ty = tid >> 4;
  const int kbeg = blockIdx.z * kchunk;
  const int kend = min(K, kbeg + kchunk);
  double* dst = part + (size_t)blockIdx.z * M * Ncol;

  double acc[4][4];
  #pragma unroll
  for (int i=0;i<4;i++)
    #pragma unroll
    for (int j=0;j<4;j++) acc[i][j] = 0.0;

  const int nkt = (kend - kbeg + 15) >> 4;
  for (int kt = 0; kt < nkt; kt++){
    const int k0 = kbeg + (kt << 4);
    __syncthreads();
    #pragma unroll
    for (int c=0;c<4;c++){
      int lin = tid + c*256;
      int row = lin >> 4, col = lin & 15;
      int gm = m0 + row, gk = k0 + col;
      double va = 0.0, vb = 0.0;
      if (gm < M && gk < kend)        va = (double)A [(size_t)gm*lda + gk];
      if (n0+row < Ncol && gk < kend) vb = Bt[(size_t)(n0+row)*ldb + gk];
      lA[row][col] = va;
      lB[row][col] = vb;
    }
    __syncthreads();
    #pragma unroll 4
    for (int kk=0; kk<16; kk+=2){
      double2 A0 = *(const double2*)&lA[ty   ][kk];
      double2 A1 = *(const double2*)&lA[ty+16][kk];
      double2 A2 = *(const double2*)&lA[ty+32][kk];
      double2 A3 = *(const double2*)&lA[ty+48][kk];
      double2 B0 = *(const double2*)&lB[tx   ][kk];
      double2 B1 = *(const double2*)&lB[tx+16][kk];
      double2 B2 = *(const double2*)&lB[tx+32][kk];
      double2 B3 = *(const double2*)&lB[tx+48][kk];
      acc[0][0]+=A0.x*B0.x; acc[0][1]+=A0.x*B1.x; acc[0][2]+=A0.x*B2.x; acc[0][3]+=A0.x*B3.x;
      acc[1][0]+=A1.x*B0.x; acc[1][1]+=A1.x*B1.x; acc[1][2]+=A1.x*B2.x; acc[1][3]+=A1.x*B3.x;
      acc[2][0]+=A2.x*B0.x; acc[2][1]+=A2.x*B1.x; acc[2][2]+=A2.x*B2.x; acc[2][3]+=A2.x*B3.x;
      acc[3][0]+=A3.x*B0.x; acc[3][1]+=A3.x*B1.x; acc[3][2]+=A3.x*B2.x; acc[3][3]+=A3.x*B3.x;
      acc[0][0]+=A0.y*B0.y; acc[0][1]+=A0.y*B1.y; acc[0][2]+=A0.y*B2.y; acc[0][3]+=A0.y*B3.y;
      acc[1][0]+=A1.y*B0.y; acc[1][1]+=A1.y*B1.y; acc[1][2]+=A1.y*B2.y; acc[1][3]+=A1.y*B3.y;
      acc[2][0]+=A2.y*B0.y; acc[2][1]+=A2.y*B1.y; acc[2][2]+=A2.y*B2.y; acc[2][3]+=A2.y*B3.y;
      acc[3][0]+=A3.y*B0.y; acc[3][1]+=A3.y*B1.y; acc[3][2]+=A3.y*B2.y; acc[3][3]+=A3.y*B3.y;
    }
  }
  #pragma unroll
  for (int j=0;j<4;j++){
    int gn = n0 + tx + 16*j;
    if (gn >= Ncol) continue;
    #pragma unroll
    for (int i=0;i<4;i++){
      int gm = m0 + ty + 16*i;
      if (gm >= M) continue;
      dst[(size_t)gm*Ncol + gn] = acc[i][j];
    }
  }
}

// reduce partials + bias + BN + ELU -> out (f64)
__global__ void epi64_k(const double* __restrict__ part, int nsplit, size_t pstride,
                        int M, int Ncol, const double* __restrict__ bias,
                        const float* __restrict__ gam, const float* __restrict__ bet,
                        double* __restrict__ out, int ldo)
{
  int t = blockIdx.x*256 + threadIdx.x;
  if (t >= M*Ncol) return;
  int gm = t / Ncol, gn = t - gm*Ncol;
  double v = 0.0;
  for (int s=0; s<nsplit; s++) v += part[(size_t)s*pstride + t];
  const double BNS = 0.99995000374968755261;
  v += bias[gn];
  v = v * ((double)gam[gn]*BNS) + (double)bet[gn];
  v = v > 0.0 ? v : expm1(v);
  out[(size_t)gm*ldo + gn] = v;
}

// ---------------- f32 GEMM (decoder, elu-bn to two f32 outs) ----------------
__global__ __launch_bounds__(256)
void gemm32d_k(const float* __restrict__ A, int lda,
               const float* __restrict__ Bt, int ldb,
               int M, int K, int Ncol,
               float* __restrict__ out1, int ldc,
               const float* __restrict__ bias, const float* __restrict__ gam,
               const float* __restrict__ bet, float* __restrict__ out2)
{
  __shared__ float lA[64][33];
  __shared__ float lB[64][33];
  const int tid = threadIdx.x;
  const int m0 = blockIdx.y * 64;
  const int n0 = blockIdx.x * 64;
  const int tx = tid & 15;
  const int ty = tid >> 4;

  float acc[4][4];
  #pragma unroll
  for (int i=0;i<4;i++)
    #pragma unroll
    for (int j=0;j<4;j++) acc[i][j] = 0.f;

  const int nkt = (K + 31) >> 5;
  for (int kt = 0; kt < nkt; kt++){
    const int k0 = kt << 5;
    __syncthreads();
    #pragma unroll
    for (int c=0;c<8;c++){
      int lin = tid + c*256;
      int row = lin >> 5, col = lin & 31;
      int gm = m0 + row, gk = k0 + col;
      float va = 0.f, vb = 0.f;
      if (gm < M && gk < K)        va = A [(size_t)gm*lda + gk];
      if (n0+row < Ncol && gk < K) vb = Bt[(size_t)(n0+row)*ldb + gk];
      lA[row][col] = va;
      lB[row][col] = vb;
    }
    __syncthreads();
    #pragma unroll 4
    for (int kk=0; kk<32; kk++){
      float a0=lA[ty][kk], a1=lA[ty+16][kk], a2=lA[ty+32][kk], a3=lA[ty+48][kk];
      float b0=lB[tx][kk], b1=lB[tx+16][kk], b2=lB[tx+32][kk], b3=lB[tx+48][kk];
      acc[0][0]+=a0*b0; acc[0][1]+=a0*b1; acc[0][2]+=a0*b2; acc[0][3]+=a0*b3;
      acc[1][0]+=a1*b0; acc[1][1]+=a1*b1; acc[1][2]+=a1*b2; acc[1][3]+=a1*b3;
      acc[2][0]+=a2*b0; acc[2][1]+=a2*b1; acc[2][2]+=a2*b2; acc[2][3]+=a2*b3;
      acc[3][0]+=a3*b0; acc[3][1]+=a3*b1; acc[3][2]+=a3*b2; acc[3][3]+=a3*b3;
    }
  }
  const float BNS = 0.99995000374968755f;
  #pragma unroll
  for (int j=0;j<4;j++){
    int gn = n0 + tx + 16*j;
    if (gn >= Ncol) continue;
    float bi = bias[gn];
    float gs = gam[gn]*BNS, be = bet[gn];
    #pragma unroll
    for (int i=0;i<4;i++){
      int gm = m0 + ty + 16*i;
      if (gm >= M) continue;
      float v = acc[i][j] + bi;
      v = v*gs + be; v = v > 0.f ? v : expm1f(v);
      out1[(size_t)gm*ldc + gn] = v;
      out2[(size_t)gm*ldc + gn] = v;
    }
  }
}

// ---------------- CSR build --------------------------------------------------
__global__ void csr_cnt_k(const int* __restrict__ key, int* __restrict__ cnt){
  int e = blockIdx.x*256 + threadIdx.x;
  if (e < NE) atomicAdd(&cnt[key[e]], 1);
}
__global__ __launch_bounds__(256)
void csr_scan_k(const int* __restrict__ cnt, int* __restrict__ rowptr, int* __restrict__ cursor){
  __shared__ int part[256];
  int t = threadIdx.x;
  int base = t*24;
  int loc[24]; int s=0;
  #pragma unroll
  for (int u=0;u<24;u++){
    int idx = base+u;
    int v = (idx<NN) ? cnt[idx] : 0;
    loc[u] = s; s += v;
  }
  part[t] = s;
  __syncthreads();
  if (t==0){
    int run=0;
    for (int u=0;u<256;u++){ int tmp=part[u]; part[u]=run; run+=tmp; }
  }
  __syncthreads();
  int off = part[t];
  #pragma unroll
  for (int u=0;u<24;u++){
    int idx = base+u;
    if (idx<NN){ rowptr[idx]=off+loc[u]; cursor[idx]=off+loc[u]; }
  }
  if (t==255) rowptr[NN] = off + s;
}
__global__ void csr_fill_k(const int* __restrict__ key, int* __restrict__ cursor,
                           int* __restrict__ elist){
  int e = blockIdx.x*256 + threadIdx.x;
  if (e < NE){ int pos = atomicAdd(&cursor[key[e]], 1); elist[pos] = e; }
}

// ---------------- fused per-node attention (dst-CSR, no atomics) ------------
__global__ __launch_bounds__(256)
void attn_k(double* __restrict__ QKVS, const int* __restrict__ rowptr,
            const int* __restrict__ elist, const int* __restrict__ src,
            double* __restrict__ alpha)
{
  __shared__ double lg[4][128];
  const int w = threadIdx.x >> 6;
  const int node = blockIdx.x*4 + w;
  if (node >= NN) return;
  const int lane = threadIdx.x & 63;
  const int e0 = rowptr[node], e1 = rowptr[node+1];
  const int deg = e1 - e0;
  if (deg <= 0) return;
  const double SC = 0.088388347648318447; // 1/sqrt(128)
  const double* q = QKVS + (size_t)node*512;
  double q0 = q[lane], q1 = q[lane+64];

  if (deg <= 128){
    double m = -1.0e300;
    for (int i=0;i<deg;i++){
      const double* k = QKVS + (size_t)src[elist[e0+i]]*512 + 128;
      double p = q0*k[lane] + q1*k[lane+64];
      #pragma unroll
      for (int off=32; off; off>>=1) p += __shfl_xor(p, off);
      p *= SC;
      if (lane==0) lg[w][i] = p;
      m = fmax(m, p);
    }
    double S = 0.0;
    for (int i=0;i<deg;i++){
      double ex = exp(lg[w][i] - m);
      if (lane==0) lg[w][i] = ex;
      S += ex;
    }
    double inv = 1.0 / S;
    double o0 = QKVS[(size_t)node*512 + 384 + lane];
    double o1 = QKVS[(size_t)node*512 + 448 + lane];
    for (int i=0;i<deg;i++){
      int e = elist[e0+i];
      double a = lg[w][i] * inv;
      const double* v = QKVS + (size_t)src[e]*512 + 256;
      o0 = fma(a, v[lane],    o0);
      o1 = fma(a, v[lane+64], o1);
      if (lane==0) alpha[e] = a;
    }
    QKVS[(size_t)node*512 + 384 + lane] = o0;
    QKVS[(size_t)node*512 + 448 + lane] = o1;
  } else {
    double m = -1.0e300;
    for (int i=0;i<deg;i++){
      const double* k = QKVS + (size_t)src[elist[e0+i]]*512 + 128;
      double p = q0*k[lane] + q1*k[lane+64];
      #pragma unroll
      for (int off=32; off; off>>=1) p += __shfl_xor(p, off);
      m = fmax(m, p*SC);
    }
    double S = 0.0;
    for (int i=0;i<deg;i++){
      const double* k = QKVS + (size_t)src[elist[e0+i]]*512 + 128;
      double p = q0*k[lane] + q1*k[lane+64];
      #pragma unroll
      for (int off=32; off; off>>=1) p += __shfl_xor(p, off);
      S += exp(p*SC - m);
    }
    double inv = 1.0 / S;
    double o0 = QKVS[(size_t)node*512 + 384 + lane];
    double o1 = QKVS[(size_t)node*512 + 448 + lane];
    for (int i=0;i<deg;i++){
      int e = elist[e0+i];
      const double* k = QKVS + (size_t)src[e]*512 + 128;
      double p = q0*k[lane] + q1*k[lane+64];
      #pragma unroll
      for (int off=32; off; off>>=1) p += __shfl_xor(p, off);
      double a = exp(p*SC - m) * inv;
      const double* v = QKVS + (size_t)src[e]*512 + 256;
      o0 = fma(a, v[lane],    o0);
      o1 = fma(a, v[lane+64], o1);
      if (lane==0) alpha[e] = a;
    }
    QKVS[(size_t)node*512 + 384 + lane] = o0;
    QKVS[(size_t)node*512 + 448 + lane] = o1;
  }
}

// ---------------- fused spmm over src-CSR (both graphs, no atomics) ---------
__global__ __launch_bounds__(256)
void spmm_csr_k(const double* __restrict__ QK1, const double* __restrict__ QK2,
                const int* __restrict__ rpSA, const int* __restrict__ elSA,
                const int* __restrict__ dstA, const double* __restrict__ aA,
                const int* __restrict__ rpSP, const int* __restrict__ elSP,
                const int* __restrict__ dstP, const double* __restrict__ aP,
                double* __restrict__ out, int ldo, int offo, int dorelu)
{
  const int node = blockIdx.x*4 + (threadIdx.x>>6);
  if (node >= NN) return;
  const int lane = threadIdx.x & 63;
  double a0 = 0.0, a1 = 0.0;
  for (int idx = rpSA[node]; idx < rpSA[node+1]; ++idx){
    int e = elSA[idx]; int d = dstA[e];
    if (d != node){
      double wgt = 0.5 * aA[e];
      const double* o = QK1 + (size_t)d*512 + 384;
      a0 = fma(wgt, o[lane],    a0);
      a1 = fma(wgt, o[lane+64], a1);
    }
  }
  for (int idx = rpSP[node]; idx < rpSP[node+1]; ++idx){
    int e = elSP[idx]; int d = dstP[e];
    if (d != node){
      double wgt = 0.5 * aP[e];
      const double* o = QK2 + (size_t)d*512 + 384;
      a0 = fma(wgt, o[lane],    a0);
      a1 = fma(wgt, o[lane+64], a1);
    }
  }
  if (dorelu){ a0 = fmax(a0, 0.0); a1 = fmax(a1, 0.0); }
  out[(size_t)node*ldo + offo + lane]      = a0;
  out[(size_t)node*ldo + offo + 64 + lane] = a1;
}

__global__ void att_scatter_k(const int* __restrict__ src, const int* __restrict__ dst,
                              const double* __restrict__ alpha, float* __restrict__ att)
{
  int e = blockIdx.x*256 + threadIdx.x;
  if (e >= NE) return;
  int s = src[e], d = dst[e];
  if (s == d) return;
  atomicAdd(&att[(size_t)s*NN + d], (float)alpha[e]);
}

// ---------------- MFMA bf16 2-split distance + fused per-tile top-12 --------
__global__ __launch_bounds__(256)
void distmf_k(const unsigned short* __restrict__ zXh, const unsigned short* __restrict__ zXl,
              const unsigned short* __restrict__ zNh, const unsigned short* __restrict__ zNl,
              const float* __restrict__ sxA, const float* __restrict__ syA,
              const float* __restrict__ cjA,
              float* __restrict__ candV, int* __restrict__ candI)
{
  __shared__ __align__(16) char smem[40960 + 1536];
  typedef unsigned short u16;
  u16 (*lAh)[40] = (u16(*)[40])(smem);
  u16 (*lAl)[40] = (u16(*)[40])(smem + 10240);
  u16 (*lBh)[40] = (u16(*)[40])(smem + 20480);
  u16 (*lBl)[40] = (u16(*)[40])(smem + 30720);
  float (*stile)[67] = (float(*)[67])(smem);     // overlay after K loop
  float* sSx = (float*)(smem + 40960);
  float* sSy = sSx + 128;
  float* sC  = sSy + 128;

  const int tid = threadIdx.x;
  const int m0 = blockIdx.y * 128;
  const int n0 = blockIdx.x * 128;
  const int lane = tid & 63;
  const int wave = tid >> 6;
  const int wm = wave >> 1, wn = wave & 1;
  const int lr = lane & 15;
  const int lk = (lane >> 4) * 8;

  if (tid < 128){
    int jg = n0 + tid;
    if (jg < NN){ sSx[tid]=sxA[jg]; sSy[tid]=syA[jg]; sC[tid]=cjA[jg]; }
    else        { sSx[tid]=0.f; sSy[tid]=0.f; sC[tid]=-3e38f; }
  }

  f32x4 acc[4][4];
  #pragma unroll
  for (int i=0;i<4;i++)
    #pragma unroll
    for (int j=0;j<4;j++) acc[i][j] = (f32x4){0.f,0.f,0.f,0.f};

  for (int kt = 0; kt < 8; kt++){
    const int k0 = kt << 5;
    __syncthreads();
    #pragma unroll
    for (int c=0;c<4;c++){
      int lin = tid + c*256;
      int row = lin >> 3;
      int kc = (lin & 7) << 2;
      int gm = m0 + row, gn = n0 + row;
      ushort4 vh = {0,0,0,0}, vl = {0,0,0,0}, wh = {0,0,0,0}, wl = {0,0,0,0};
      if (gm < NN){
        vh = *(const ushort4*)(zXh + (size_t)gm*256 + k0 + kc);
        vl = *(const ushort4*)(zXl + (size_t)gm*256 + k0 + kc);
      }
      if (gn < NN){
        wh = *(const ushort4*)(zNh + (size_t)gn*256 + k0 + kc);
        wl = *(const ushort4*)(zNl + (size_t)gn*256 + k0 + kc);
      }
      *(ushort4*)&lAh[row][kc] = vh;
      *(ushort4*)&lAl[row][kc] = vl;
      *(ushort4*)&lBh[row][kc] = wh;
      *(ushort4*)&lBl[row][kc] = wl;
    }
    __syncthreads();
    short8 ah[4], al[4];
    #pragma unroll
    for (int fm=0; fm<4; fm++){
      ah[fm] = *(const short8*)&lAh[wm*64 + fm*16 + lr][lk];
      al[fm] = *(const short8*)&lAl[wm*64 + fm*16 + lr][lk];
    }
    #pragma unroll
    for (int fn=0; fn<4; fn++){
      short8 bh = *(const short8*)&lBh[wn*64 + fn*16 + lr][lk];
      short8 bl = *(const short8*)&lBl[wn*64 + fn*16 + lr][lk];
      #pragma unroll
      for (int fm=0; fm<4; fm++){
        acc[fm][fn] = __builtin_amdgcn_mfma_f32_16x16x32_bf16(ah[fm], bh, acc[fm][fn], 0,0,0);
        acc[fm][fn] = __builtin_amdgcn_mfma_f32_16x16x32_bf16(ah[fm], bl, acc[fm][fn], 0,0,0);
        acc[fm][fn] = __builtin_amdgcn_mfma_f32_16x16x32_bf16(al[fm], bh, acc[fm][fn], 0,0,0);
      }
    }
  }

  float tv[NCAND]; int ti[NCAND];
  #pragma unroll
  for (int p=0;p<NCAND;p++){ tv[p] = -3.4e38f; ti[p] = -1; }
  const int gi = m0 + tid;
  float sxi = 0.f, syi = 0.f;
  if (tid < 128 && gi < NN){ sxi = sxA[gi]; syi = syA[gi]; }

  for (int jh = 0; jh < 2; jh++){
    __syncthreads();
    if (wn == jh){
      #pragma unroll
      for (int fm=0;fm<4;fm++){
        #pragma unroll
        for (int fn=0;fn<4;fn++){
          int lrow = wm*64 + fm*16 + ((lane>>4)<<2);
          int lcol = fn*16 + lr;
          #pragma unroll
          for (int r=0;r<4;r++)
            stile[lrow + r][lcol] = acc[fm][fn][r];
        }
      }
    }
    __syncthreads();
    if (tid < 128 && gi < NN){
      #pragma unroll 1
      for (int jj=0; jj<64; jj++){
        int j = jh*64 + jj;
        float s = 2.f*stile[tid][jj] + 2.f*(sxi*sSx[j] + syi*sSy[j]) + sC[j];
        if (s > tv[NCAND-1]){
          bool g[NCAND];
          #pragma unroll
          for (int p=0;p<NCAND;p++) g[p] = s > tv[p];
          #pragma unroll
          for (int p=NCAND-1;p>0;--p) if (g[p-1]){ tv[p]=tv[p-1]; ti[p]=ti[p-1]; }
          #pragma unroll
          for (int p=0;p<NCAND;p++){ bool pl = g[p] && (p==0 || !g[p-1]); if (pl){ tv[p]=s; ti[p]=n0+j; } }
        }
      }
    }
  }
  if (tid < 128 && gi < NN){
    size_t base = ((size_t)gi*NTILE + blockIdx.x)*NCAND;
    #pragma unroll
    for (int p=0;p<NCAND;p++){ candV[base+p]=tv[p]; candI[base+p]=ti[p]; }
  }
}

// ---------------- merge: 32x block-argmax prefilter -> f64 rescore -> top-9 -
__global__ __launch_bounds__(256)
void merge64_k(const float* __restrict__ candV, const int* __restrict__ candI,
               const double* __restrict__ Z, const double* __restrict__ Znb,
               const double* __restrict__ sx64, const double* __restrict__ sy64,
               double* __restrict__ wgt9, int* __restrict__ idx9)
{
  __shared__ double zi[256];
  __shared__ int    fjS[TCAND];
  __shared__ float  wbv[4];
  __shared__ int    wbc[4];
  __shared__ int    chosen;
  __shared__ int    pj[PRE];
  __shared__ double ps[PRE];

  const int i = blockIdx.x;
  const int t = threadIdx.x;
  const int lane = t & 63, wv = t >> 6;

  zi[t] = Z[(size_t)i*256 + t];

  float v0 = -3.4e38f, v1 = -3.4e38f, v2 = -3.4e38f;
  const int c0 = t, c1 = t + 256, c2 = t + 512;
  {
    float vv = candV[(size_t)i*TCAND + c0];
    int jj = candI[(size_t)i*TCAND + c0];
    fjS[c0] = jj;
    if (jj >= 0) v0 = vv;
  }
  if (c1 < TCAND){
    float vv = candV[(size_t)i*TCAND + c1];
    int jj = candI[(size_t)i*TCAND + c1];
    fjS[c1] = jj;
    if (jj >= 0) v1 = vv;
  }
  if (c2 < TCAND){
    float vv = candV[(size_t)i*TCAND + c2];
    int jj = candI[(size_t)i*TCAND + c2];
    fjS[c2] = jj;
    if (jj >= 0) v2 = vv;
  }
  __syncthreads();

  for (int it = 0; it < PRE; it++){
    float bv = v0; int bc = c0;
    if (v1 > bv || (v1 == bv && c1 < bc)){ bv = v1; bc = c1; }
    if (v2 > bv || (v2 == bv && c2 < bc)){ bv = v2; bc = c2; }
    #pragma unroll
    for (int off = 32; off; off >>= 1){
      float ov = __shfl_xor(bv, off);
      int   oc = __shfl_xor(bc, off);
      if (ov > bv || (ov == bv && oc < bc)){ bv = ov; bc = oc; }
    }
    if (lane == 0){ wbv[wv] = bv; wbc[wv] = bc; }
    __syncthreads();
    if (t == 0){
      float gb = wbv[0]; int gc = wbc[0];
      #pragma unroll
      for (int w2 = 1; w2 < 4; w2++)
        if (wbv[w2] > gb || (wbv[w2] == gb && wbc[w2] < gc)){ gb = wbv[w2]; gc = wbc[w2]; }
      chosen = gc;
      pj[it] = fjS[gc];
    }
    __syncthreads();
    int gc = chosen;
    if (c0 == gc) v0 = -3.4e38f;
    if (c1 == gc) v1 = -3.4e38f;
    if (c2 == gc) v2 = -3.4e38f;
  }

  const double sxi = sx64[i], syi = sy64[i];
  for (int c = wv; c < PRE; c += 4){
    int j = pj[c];
    const double* zj = Znb + (size_t)j*256;
    double p = 0.0;
    #pragma unroll
    for (int u = 0; u < 4; u++){
      double b = zj[lane + 64*u];
      double a = zi[lane + 64*u];
      p = fma(2.0*a - b, b, p);     // += 2ab - b^2
    }
    #pragma unroll
    for (int off = 32; off; off >>= 1) p += __shfl_xor(p, off);
    double sxj = sx64[j], syj = sy64[j];
    double s = p + 2.0*(sxi*sxj + syi*syj) - (sxj*sxj + syj*syj);
    if (lane == 0) ps[c] = s;
  }
  __syncthreads();

  if (t == 0){
    double tv9[9]; int ti9[9];
    #pragma unroll
    for (int p = 0; p < 9; p++){ tv9[p] = -1.0e301; ti9[p] = 0x7FFFFFFF; }
    for (int c = 0; c < PRE; c++){
      double s = ps[c]; int j = pj[c];
      if (!((s > tv9[8]) || (s == tv9[8] && j < ti9[8]))) continue;
      int p = 8;
      while (p > 0 && ((s > tv9[p-1]) || (s == tv9[p-1] && j < ti9[p-1]))){
        tv9[p] = tv9[p-1]; ti9[p] = ti9[p-1]; --p;
      }
      tv9[p] = s; ti9[p] = j;
    }
    double m = tv9[0], e[9], S = 0.0;
    #pragma unroll
    for (int k = 0; k < 9; k++){ e[k] = exp(tv9[k] - m); S += e[k]; }
    #pragma unroll
    for (int k = 0; k < 9; k++){
      wgt9[(size_t)i*9 + k] = e[k] / S;
      idx9[(size_t)i*9 + k] = ti9[k];
    }
  }
}

// ---------------- znb prep + casts ------------------------------------------
__global__ __launch_bounds__(256)
void znbprep_k(const double* __restrict__ znb, const double* __restrict__ ssq64,
               float* __restrict__ cjA)
{
  __shared__ double red[256];
  int i = blockIdx.x, d = threadIdx.x;
  double v = znb[(size_t)i*256 + d];
  red[d] = v*v;
  __syncthreads();
  for (int s=128; s; s>>=1){ if (d<s) red[d]+=red[d+s]; __syncthreads(); }
  if (d==0) cjA[i] = -(float)(red[0] + ssq64[i]);
}
__global__ void featout_k(const double* __restrict__ z, float* __restrict__ o){
  int t = blockIdx.x*256+threadIdx.x;
  if (t < NN*128){ int i=t>>7, d=t&127; o[t] = (float)z[(size_t)i*256 + d]; }
}

__global__ __launch_bounds__(256)
void zout_k(const double* __restrict__ Z, const double* __restrict__ Znb,
            const int* __restrict__ idx9, const double* __restrict__ wgt9,
            float* __restrict__ zoOut, float* __restrict__ zoF32, float* __restrict__ x1)
{
  int i = blockIdx.x; int d = threadIdx.x;
  double a = Z[(size_t)i*256 + d];
  #pragma unroll
  for (int k=0;k<9;k++){
    int j = idx9[(size_t)i*9+k];
    double w = wgt9[(size_t)i*9+k];
    double t = w * Znb[(size_t)j*256 + d];
    a += t;
    x1[((size_t)i*9+k)*256 + d] = (float)t;
  }
  float af = (float)a;
  zoOut[(size_t)i*256+d] = af;
  zoF32[(size_t)i*256+d] = af;
}

__global__ __launch_bounds__(256)
void q_k(const float* __restrict__ zoF, const float* __restrict__ clus, float* __restrict__ qB)
{
  __shared__ float wred[10][4];
  __shared__ float qs[10];
  int i = blockIdx.x, d = threadIdx.x;
  int lane = d & 63, wv = d >> 6;
  float zo = zoF[(size_t)i*256 + d];
  #pragma unroll
  for (int c=0;c<10;c++){
    float df = zo - clus[(size_t)c*256 + d];
    float p = df*df;
    #pragma unroll
    for (int off=32; off; off>>=1) p += __shfl_down(p, off);
    if (lane == 0) wred[c][wv] = p;
  }
  __syncthreads();
  if (d < 10){
    float d2 = wred[d][0]+wred[d][1]+wred[d][2]+wred[d][3];
    qs[d] = 1.f/(1.f + d2);
  }
  __syncthreads();
  if (d < 10){
    float s = 0.f;
    #pragma unroll
    for (int c=0;c<10;c++) s += qs[c];
    qB[(size_t)i*10 + d] = qs[d]/s;
  }
}

// ---------------- host ------------------------------------------------------
extern "C" void kernel_launch(void* const* d_in, const int* in_sizes, int n_in,
                              void* d_out, int out_size, void* d_ws, size_t ws_size,
                              hipStream_t stream)
{
  (void)in_sizes; (void)n_in; (void)out_size; (void)ws_size;
  const float* x    = (const float*)d_in[0];
  const float* xnb  = (const float*)d_in[1];
  const float* spat = (const float*)d_in[2];
  const int*   adj  = (const int*)d_in[3];
  const int*   adjp = (const int*)d_in[4];
  const float* W1   = (const float*)d_in[5];
  const float* b1   = (const float*)d_in[6];
  const float* g1   = (const float*)d_in[7];
  const float* be1  = (const float*)d_in[8];
  const float* W2   = (const float*)d_in[9];
  const float* b2   = (const float*)d_in[10];
  const float* g2   = (const float*)d_in[11];
  const float* be2  = (const float*)d_in[12];
  const float* Wq   = (const float*)d_in[13];
  const float* Wk   = (const float*)d_in[14];
  const float* Wv   = (const float*)d_in[15];
  const float* Wsm  = (const float*)d_in[16];
  const float* bq   = (const float*)d_in[17];
  const float* bk   = (const float*)d_in[18];
  const float* bv   = (const float*)d_in[19];
  const float* bs   = (const float*)d_in[20];
  const float* decW = (const float*)d_in[21];
  const float* decb = (const float*)d_in[22];
  const float* decg = (const float*)d_in[23];
  const float* decbe= (const float*)d_in[24];
  const float* clus = (const float*)d_in[25];
  float* outF = (float*)d_out;
  const int* srcA = adj,  *dstA = adj + NE;
  const int* srcP = adjp, *dstP = adjp + NE;

  char* wsb = (char*)d_ws;
  size_t off = 0;
  auto alloc = [&](size_t bytes)->char*{
    char* p = wsb + off;
    off = (off + bytes + 255) & ~(size_t)255;
    return p;
  };
  double* W1t  = (double*)alloc(768000*8);
  double* W2t  = (double*)alloc(32768*8);
  double* Bct  = (double*)alloc(196608*8);
  float*  Dt   = (float*) alloc(768000*4);
  double* bcat = (double*)alloc(1536*8);
  double* sx64 = (double*)alloc(NN*8);
  double* sy64 = (double*)alloc(NN*8);
  double* ssq64= (double*)alloc(NN*8);
  float*  sx32 = (float*) alloc(NN*4);
  float*  sy32 = (float*) alloc(NN*4);
  double* b1c  = (double*)alloc(256*8);
  double* b2c  = (double*)alloc(128*8);
  double* H1   = (double*)alloc((size_t)NN*256*8);
  double* zX64 = (double*)alloc((size_t)NN*256*8);
  double* zNB64= (double*)alloc((size_t)NN*256*8);
  double* hcur = (double*)alloc((size_t)NN*128*8);
  double* QK1  = (double*)alloc((size_t)NN*512*8);
  double* QK2  = (double*)alloc((size_t)NN*512*8);
  double* alphaA=(double*)alloc((size_t)NE*8);
  double* alphaP=(double*)alloc((size_t)NE*8);
  double* part = (double*)alloc((size_t)4*NN*256*8);   // split-K partials (49 MB)
  // CSRs
  int* rpDA = (int*)alloc((NN+1)*4);
  int* rpDP = (int*)alloc((NN+1)*4);
  int* rpSA = (int*)alloc((NN+1)*4);
  int* rpSP = (int*)alloc((NN+1)*4);
  int* curDA= (int*)alloc(NN*4);
  int* curDP= (int*)alloc(NN*4);
  int* curSA= (int*)alloc(NN*4);
  int* curSP= (int*)alloc(NN*4);
  int* elDA = (int*)alloc(NE*4);
  int* elDP = (int*)alloc(NE*4);
  int* elSA = (int*)alloc(NE*4);
  int* elSP = (int*)alloc(NE*4);
  unsigned short* zXh = (unsigned short*)alloc((size_t)NN*256*2);
  unsigned short* zXl = (unsigned short*)alloc((size_t)NN*256*2);
  unsigned short* zNh = (unsigned short*)alloc((size_t)NN*256*2);
  unsigned short* zNl = (unsigned short*)alloc((size_t)NN*256*2);
  float*  cjA  = (float*) alloc(NN*4);
  float*  candV= (float*) alloc((size_t)NN*TCAND*4);
  int*    candI= (int*)   alloc((size_t)NN*TCAND*4);
  int*    idx9 = (int*)   alloc((size_t)NN*9*4);
  double* wgt9 = (double*)alloc((size_t)NN*9*8);
  float*  zoF32= (float*) alloc((size_t)NN*256*4);

  prep_k<<<6926, 256, 0, stream>>>(W1, W2, Wq, Wk, Wv, Wsm, bq, bk, bv, bs, decW, spat,
                                   W1t, W2t, Bct, Dt, bcat,
                                   sx64, sy64, ssq64, sx32, sy32);
  castup_k<<<1, 256, 0, stream>>>(b1, b1c, 256);
  castup_k<<<1, 256, 0, stream>>>(b2, b2c, 128);

  // CSR build (4 CSRs)
  hipMemsetAsync(curDA, 0, NN*4, stream);
  hipMemsetAsync(curDP, 0, NN*4, stream);
  hipMemsetAsync(curSA, 0, NN*4, stream);
  hipMemsetAsync(curSP, 0, NN*4, stream);
  csr_cnt_k<<<375, 256, 0, stream>>>(dstA, curDA);
  csr_cnt_k<<<375, 256, 0, stream>>>(dstP, curDP);
  csr_cnt_k<<<375, 256, 0, stream>>>(srcA, curSA);
  csr_cnt_k<<<375, 256, 0, stream>>>(srcP, curSP);
  csr_scan_k<<<1, 256, 0, stream>>>(curDA, rpDA, curDA);
  csr_scan_k<<<1, 256, 0, stream>>>(curDP, rpDP, curDP);
  csr_scan_k<<<1, 256, 0, stream>>>(curSA, rpSA, curSA);
  csr_scan_k<<<1, 256, 0, stream>>>(curSP, rpSP, curSP);
  csr_fill_k<<<375, 256, 0, stream>>>(dstA, curDA, elDA);
  csr_fill_k<<<375, 256, 0, stream>>>(dstP, curDP, elDP);
  csr_fill_k<<<375, 256, 0, stream>>>(srcA, curSA, elSA);
  csr_fill_k<<<375, 256, 0, stream>>>(srcP, curSP, elSP);

  auto enc = [&](const float* xin, double* zbuf, bool isX){
    gemm64s_k<float><<<dim3(4,94,4), 256, 0, stream>>>(xin, KDIN, W1t, KDIN,
                                                       NN, KDIN, 768, 256, part);
    epi64_k<<<(NN*256+255)/256, 256, 0, stream>>>(part, 4, (size_t)NN*256,
                                                  NN, 256, b1c, g1, be1, H1, 256);
    gemm64s_k<double><<<dim3(2,94,4), 256, 0, stream>>>(H1, 256, W2t, 256,
                                                        NN, 256, 64, 128, part);
    epi64_k<<<(NN*128+255)/256, 256, 0, stream>>>(part, 4, (size_t)NN*128,
                                                  NN, 128, b2c, g2, be2, zbuf, 256);
    const double* hin = zbuf; int ldh = 256;
    for (int l=0; l<3; l++){
      const double* Bh = Bct + (size_t)l*65536;
      const double* bc = bcat + l*512;
      if (l != 1){
        gemm64_k<0,double><<<dim3(8,94), 256, 0, stream>>>(hin, ldh, Bh, 128, NN, 128, 512,
                                                           QK1, 512, bc, nullptr, nullptr, QK2);
        attn_k<<<1500, 256, 0, stream>>>(QK1, rpDA, elDA, srcA, alphaA);
        attn_k<<<1500, 256, 0, stream>>>(QK2, rpDP, elDP, srcP, alphaP);
      } else {
        gemm64_k<0,double><<<dim3(8,94), 256, 0, stream>>>(hin, ldh, Bh, 128, NN, 128, 512,
                                                           QK1, 512, bc, nullptr, nullptr, nullptr);
        attn_k<<<1500, 256, 0, stream>>>(QK1, rpDA, elDA, srcA, alphaA);
        gemm64_k<0,double><<<dim3(8,94), 256, 0, stream>>>(QK1 + 384, 512, Bh, 128, NN, 128, 512,
                                                           QK2, 512, bc, nullptr, nullptr, nullptr);
        attn_k<<<1500, 256, 0, stream>>>(QK2, rpDP, elDP, srcP, alphaP);
      }
      if (isX && l == 2){
        hipMemsetAsync(outF + (size_t)OFF_ATT, 0, (size_t)NN*NN*4, stream);
        att_scatter_k<<<375, 256, 0, stream>>>(srcP, dstP, alphaP, outF + (size_t)OFF_ATT);
      }
      if (l < 2){
        spmm_csr_k<<<1500, 256, 0, stream>>>(QK1, QK2, rpSA, elSA, dstA, alphaA,
                                             rpSP, elSP, dstP, alphaP, hcur, 128, 0, 1);
        hin = hcur; ldh = 128;
      } else {
        spmm_csr_k<<<1500, 256, 0, stream>>>(QK1, QK2, rpSA, elSA, dstA, alphaA,
                                             rpSP, elSP, dstP, alphaP, zbuf, 256, 128, 0);
      }
    }
  };
  enc(x,   zX64,  true);
  enc(xnb, zNB64, false);

  splitz_k<<<6000, 256, 0, stream>>>(zX64,  zXh, zXl, NN*256);
  splitz_k<<<6000, 256, 0, stream>>>(zNB64, zNh, zNl, NN*256);
  znbprep_k<<<NN, 256, 0, stream>>>(zNB64, ssq64, cjA);
  distmf_k<<<dim3(NTILE,47), 256, 0, stream>>>(zXh, zXl, zNh, zNl,
                                               sx32, sy32, cjA, candV, candI);
  merge64_k<<<NN, 256, 0, stream>>>(candV, candI, zX64, zNB64, sx64, sy64, wgt9, idx9);

  zout_k<<<NN, 256, 0, stream>>>(zX64, zNB64, idx9, wgt9,
                                 outF + (size_t)OFF_ZOUT, zoF32, outF + (size_t)OFF_X1);
  gemm32d_k<<<dim3(47,94), 256, 0, stream>>>(zoF32, 256, Dt, 256, NN, 256, 3000,
                                             outF + (size_t)OFF_DE1, 3000, decb, decg, decbe,
                                             outF + (size_t)OFF_DE2);
  q_k<<<NN, 256, 0, stream>>>(zoF32, clus, outF + (size_t)OFF_Q);
  featout_k<<<3000, 256, 0, stream>>>(zX64, outF + (size_t)OFF_FEAT);
}

// Round 19
// 2658.050 us; speedup vs baseline: 1.0799x; 1.0764x over previous
//
#include <hip/hip_runtime.h>
#include <hip/hip_bf16.h>
#include <math.h>
#include <stdint.h>

#define NN 6000
#define NE 96000
#define KDIN 3000
#define NCAND 12            // candidates per 128-col tile
#define NTILE 47
#define TCAND (NCAND*NTILE) // 564 per row
#define PRE 32              // f64-rescored candidates per row

// output element offsets (d_out is FLOAT32)
#define OFF_ZOUT 0
#define OFF_DE1  1536000
#define OFF_Q    19536000
#define OFF_FEAT 19596000
#define OFF_DE2  20364000
#define OFF_X1   38364000
#define OFF_ATT  52188000

typedef __attribute__((ext_vector_type(8))) short short8;
typedef __attribute__((ext_vector_type(4))) float f32x4;

__device__ __forceinline__ unsigned short f2bf(float f){
  unsigned int u = __float_as_uint(f);
  u += 0x7FFFu + ((u >> 16) & 1u);
  return (unsigned short)(u >> 16);
}
__device__ __forceinline__ float bf2f(unsigned short h){
  return __uint_as_float(((unsigned int)h) << 16);
}

// ---------------- weight prep: transpose, cast to f64 -----------------------
__global__ void prep_k(const float* __restrict__ W1, const float* __restrict__ W2,
                       const float* __restrict__ Wq, const float* __restrict__ Wk,
                       const float* __restrict__ Wv, const float* __restrict__ Ws,
                       const float* __restrict__ bq, const float* __restrict__ bk,
                       const float* __restrict__ bv, const float* __restrict__ bs,
                       const float* __restrict__ decW, const float* __restrict__ spat,
                       double* __restrict__ W1t, double* __restrict__ W2t,
                       double* __restrict__ Bct, float* __restrict__ Dt,
                       double* __restrict__ bcat,
                       double* __restrict__ sx64, double* __restrict__ sy64,
                       double* __restrict__ ssq64,
                       float* __restrict__ sx32, float* __restrict__ sy32)
{
  int t = blockIdx.x * 256 + threadIdx.x;
  if (t < 768000){
    int n = t / 3000, k = t % 3000;
    W1t[t] = (double)W1[(size_t)k * 256 + n]; return;
  }
  t -= 768000;
  if (t < 32768){
    int n = t / 256, k = t % 256;
    W2t[t] = (double)W2[(size_t)k * 128 + n]; return;
  }
  t -= 32768;
  if (t < 196608){
    int l = t / 65536; int rem = t % 65536;
    int n = rem / 128, k = rem % 128;
    int sel = n >> 7, nn = n & 127;
    const float* Wm = sel==0 ? Wq : sel==1 ? Wk : sel==2 ? Wv : Ws;
    Bct[t] = (double)Wm[((size_t)(l*128) + k) * 128 + nn]; return;
  }
  t -= 196608;
  if (t < 768000){
    int n = t / 256, k = t % 256;
    Dt[t] = decW[(size_t)k * 3000 + n]; return;
  }
  t -= 768000;
  if (t < 1536){
    int l = t / 512, n = t % 512;
    int sel = n >> 7, nn = n & 127;
    const float* bm = sel==0 ? bq : sel==1 ? bk : sel==2 ? bv : bs;
    bcat[t] = (double)bm[l*128 + nn]; return;
  }
  t -= 1536;
  if (t < NN){
    float sx = spat[(size_t)t*2], sy = spat[(size_t)t*2+1];
    sx64[t]=(double)sx; sy64[t]=(double)sy;
    ssq64[t]=(double)sx*(double)sx + (double)sy*(double)sy;
    sx32[t]=sx; sy32[t]=sy; return;
  }
}

__global__ void castup_k(const float* __restrict__ s, double* __restrict__ d, int n){
  int t = blockIdx.x*256 + threadIdx.x;
  if (t < n) d[t] = (double)s[t];
}

// split f64 z -> bf16 hi/lo (via f32)
__global__ void splitz_k(const double* __restrict__ z64, unsigned short* __restrict__ zh,
                         unsigned short* __restrict__ zl, int n){
  int t = blockIdx.x*256 + threadIdx.x;
  if (t < n){
    float v = (float)z64[t];
    unsigned short h = f2bf(v);
    float r = v - bf2f(h);
    zh[t] = h; zl[t] = f2bf(r);
  }
}

// ---------------- f64 vector GEMM, NT, 64x64, BK=16, double2 LDS reads ------
template<int EPI, typename TA>
__global__ __launch_bounds__(256)
void gemm64_k(const TA* __restrict__ A, int lda,
              const double* __restrict__ Bt, int ldb,
              int M, int K, int Ncol,
              double* __restrict__ outF, int ldc,
              const double* __restrict__ bias,
              const float* __restrict__ gam, const float* __restrict__ bet,
              double* __restrict__ outF2)
{
  __shared__ double lA[64][18];
  __shared__ double lB[64][18];
  const int tid = threadIdx.x;
  const int m0 = blockIdx.y * 64;
  const int n0 = blockIdx.x * 64;
  const int tx = tid & 15;
  const int ty = tid >> 4;

  double acc[4][4];
  #pragma unroll
  for (int i=0;i<4;i++)
    #pragma unroll
    for (int j=0;j<4;j++) acc[i][j] = 0.0;

  const int nkt = (K + 15) >> 4;
  for (int kt = 0; kt < nkt; kt++){
    const int k0 = kt << 4;
    __syncthreads();
    #pragma unroll
    for (int c=0;c<4;c++){
      int lin = tid + c*256;
      int row = lin >> 4, col = lin & 15;
      int gm = m0 + row, gk = k0 + col;
      double va = 0.0, vb = 0.0;
      if (gm < M && gk < K)        va = (double)A [(size_t)gm*lda + gk];
      if (n0+row < Ncol && gk < K) vb = Bt[(size_t)(n0+row)*ldb + gk];
      lA[row][col] = va;
      lB[row][col] = vb;
    }
    __syncthreads();
    #pragma unroll 4
    for (int kk=0; kk<16; kk+=2){
      double2 A0 = *(const double2*)&lA[ty   ][kk];
      double2 A1 = *(const double2*)&lA[ty+16][kk];
      double2 A2 = *(const double2*)&lA[ty+32][kk];
      double2 A3 = *(const double2*)&lA[ty+48][kk];
      double2 B0 = *(const double2*)&lB[tx   ][kk];
      double2 B1 = *(const double2*)&lB[tx+16][kk];
      double2 B2 = *(const double2*)&lB[tx+32][kk];
      double2 B3 = *(const double2*)&lB[tx+48][kk];
      acc[0][0]+=A0.x*B0.x; acc[0][1]+=A0.x*B1.x; acc[0][2]+=A0.x*B2.x; acc[0][3]+=A0.x*B3.x;
      acc[1][0]+=A1.x*B0.x; acc[1][1]+=A1.x*B1.x; acc[1][2]+=A1.x*B2.x; acc[1][3]+=A1.x*B3.x;
      acc[2][0]+=A2.x*B0.x; acc[2][1]+=A2.x*B1.x; acc[2][2]+=A2.x*B2.x; acc[2][3]+=A2.x*B3.x;
      acc[3][0]+=A3.x*B0.x; acc[3][1]+=A3.x*B1.x; acc[3][2]+=A3.x*B2.x; acc[3][3]+=A3.x*B3.x;
      acc[0][0]+=A0.y*B0.y; acc[0][1]+=A0.y*B1.y; acc[0][2]+=A0.y*B2.y; acc[0][3]+=A0.y*B3.y;
      acc[1][0]+=A1.y*B0.y; acc[1][1]+=A1.y*B1.y; acc[1][2]+=A1.y*B2.y; acc[1][3]+=A1.y*B3.y;
      acc[2][0]+=A2.y*B0.y; acc[2][1]+=A2.y*B1.y; acc[2][2]+=A2.y*B2.y; acc[2][3]+=A2.y*B3.y;
      acc[3][0]+=A3.y*B0.y; acc[3][1]+=A3.y*B1.y; acc[3][2]+=A3.y*B2.y; acc[3][3]+=A3.y*B3.y;
    }
  }
  #pragma unroll
  for (int j=0;j<4;j++){
    int gn = n0 + tx + 16*j;
    if (gn >= Ncol) continue;
    double bi = bias[gn];
    #pragma unroll
    for (int i=0;i<4;i++){
      int gm = m0 + ty + 16*i;
      if (gm >= M) continue;
      double v = acc[i][j] + bi;
      outF[(size_t)gm*ldc + gn] = v;
      if (outF2) outF2[(size_t)gm*ldc + gn] = v;
    }
  }
}

// ---------------- split-K f64 GEMM (BK=16), two A sources -------------------
template<typename TA>
__global__ __launch_bounds__(256)
void gemm64s_k(const TA* __restrict__ A, const TA* __restrict__ A2, int M1, int lda,
               const double* __restrict__ Bt, int ldb,
               int M, int K, int kchunk, int Ncol,
               double* __restrict__ part)   // [z][M*Ncol]
{
  __shared__ double lA[64][18];
  __shared__ double lB[64][18];
  const int tid = threadIdx.x;
  const int m0 = blockIdx.y * 64;
  const int n0 = blockIdx.x * 64;
  const int tx = tid & 15;
  const int ty = tid >> 4;
  const int kbeg = blockIdx.z * kchunk;
  const int kend = min(K, kbeg + kchunk);
  double* dst = part + (size_t)blockIdx.z * M * Ncol;

  double acc[4][4];
  #pragma unroll
  for (int i=0;i<4;i++)
    #pragma unroll
    for (int j=0;j<4;j++) acc[i][j] = 0.0;

  const int nkt = (kend - kbeg + 15) >> 4;
  for (int kt = 0; kt < nkt; kt++){
    const int k0 = kbeg + (kt << 4);
    __syncthreads();
    #pragma unroll
    for (int c=0;c<4;c++){
      int lin = tid + c*256;
      int row = lin >> 4, col = lin & 15;
      int gm = m0 + row, gk = k0 + col;
      double va = 0.0, vb = 0.0;
      if (gm < M && gk < kend){
        va = (gm < M1) ? (double)A[(size_t)gm*lda + gk]
                       : (double)A2[(size_t)(gm-M1)*lda + gk];
      }
      if (n0+row < Ncol && gk < kend) vb = Bt[(size_t)(n0+row)*ldb + gk];
      lA[row][col] = va;
      lB[row][col] = vb;
    }
    __syncthreads();
    #pragma unroll 4
    for (int kk=0; kk<16; kk+=2){
      double2 A0 = *(const double2*)&lA[ty   ][kk];
      double2 A1 = *(const double2*)&lA[ty+16][kk];
      double2 A2v = *(const double2*)&lA[ty+32][kk];
      double2 A3 = *(const double2*)&lA[ty+48][kk];
      double2 B0 = *(const double2*)&lB[tx   ][kk];
      double2 B1 = *(const double2*)&lB[tx+16][kk];
      double2 B2 = *(const double2*)&lB[tx+32][kk];
      double2 B3 = *(const double2*)&lB[tx+48][kk];
      acc[0][0]+=A0.x*B0.x; acc[0][1]+=A0.x*B1.x; acc[0][2]+=A0.x*B2.x; acc[0][3]+=A0.x*B3.x;
      acc[1][0]+=A1.x*B0.x; acc[1][1]+=A1.x*B1.x; acc[1][2]+=A1.x*B2.x; acc[1][3]+=A1.x*B3.x;
      acc[2][0]+=A2v.x*B0.x; acc[2][1]+=A2v.x*B1.x; acc[2][2]+=A2v.x*B2.x; acc[2][3]+=A2v.x*B3.x;
      acc[3][0]+=A3.x*B0.x; acc[3][1]+=A3.x*B1.x; acc[3][2]+=A3.x*B2.x; acc[3][3]+=A3.x*B3.x;
      acc[0][0]+=A0.y*B0.y; acc[0][1]+=A0.y*B1.y; acc[0][2]+=A0.y*B2.y; acc[0][3]+=A0.y*B3.y;
      acc[1][0]+=A1.y*B0.y; acc[1][1]+=A1.y*B1.y; acc[1][2]+=A1.y*B2.y; acc[1][3]+=A1.y*B3.y;
      acc[2][0]+=A2v.y*B0.y; acc[2][1]+=A2v.y*B1.y; acc[2][2]+=A2v.y*B2.y; acc[2][3]+=A2v.y*B3.y;
      acc[3][0]+=A3.y*B0.y; acc[3][1]+=A3.y*B1.y; acc[3][2]+=A3.y*B2.y; acc[3][3]+=A3.y*B3.y;
    }
  }
  #pragma unroll
  for (int j=0;j<4;j++){
    int gn = n0 + tx + 16*j;
    if (gn >= Ncol) continue;
    #pragma unroll
    for (int i=0;i<4;i++){
      int gm = m0 + ty + 16*i;
      if (gm >= M) continue;
      dst[(size_t)gm*Ncol + gn] = acc[i][j];
    }
  }
}

// reduce partials + bias + BN + ELU -> out (f64)
__global__ void epi64_k(const double* __restrict__ part, int nsplit, size_t pstride,
                        int M, int Ncol, const double* __restrict__ bias,
                        const float* __restrict__ gam, const float* __restrict__ bet,
                        double* __restrict__ out, int ldo)
{
  int t = blockIdx.x*256 + threadIdx.x;
  if (t >= M*Ncol) return;
  int gm = t / Ncol, gn = t - gm*Ncol;
  double v = 0.0;
  for (int s=0; s<nsplit; s++) v += part[(size_t)s*pstride + t];
  const double BNS = 0.99995000374968755261;
  v += bias[gn];
  v = v * ((double)gam[gn]*BNS) + (double)bet[gn];
  v = v > 0.0 ? v : expm1(v);
  out[(size_t)gm*ldo + gn] = v;
}

// ---------------- f32 GEMM (decoder, elu-bn to two f32 outs) ----------------
__global__ __launch_bounds__(256)
void gemm32d_k(const float* __restrict__ A, int lda,
               const float* __restrict__ Bt, int ldb,
               int M, int K, int Ncol,
               float* __restrict__ out1, int ldc,
               const float* __restrict__ bias, const float* __restrict__ gam,
               const float* __restrict__ bet, float* __restrict__ out2)
{
  __shared__ float lA[64][33];
  __shared__ float lB[64][33];
  const int tid = threadIdx.x;
  const int m0 = blockIdx.y * 64;
  const int n0 = blockIdx.x * 64;
  const int tx = tid & 15;
  const int ty = tid >> 4;

  float acc[4][4];
  #pragma unroll
  for (int i=0;i<4;i++)
    #pragma unroll
    for (int j=0;j<4;j++) acc[i][j] = 0.f;

  const int nkt = (K + 31) >> 5;
  for (int kt = 0; kt < nkt; kt++){
    const int k0 = kt << 5;
    __syncthreads();
    #pragma unroll
    for (int c=0;c<8;c++){
      int lin = tid + c*256;
      int row = lin >> 5, col = lin & 31;
      int gm = m0 + row, gk = k0 + col;
      float va = 0.f, vb = 0.f;
      if (gm < M && gk < K)        va = A [(size_t)gm*lda + gk];
      if (n0+row < Ncol && gk < K) vb = Bt[(size_t)(n0+row)*ldb + gk];
      lA[row][col] = va;
      lB[row][col] = vb;
    }
    __syncthreads();
    #pragma unroll 4
    for (int kk=0; kk<32; kk++){
      float a0=lA[ty][kk], a1=lA[ty+16][kk], a2=lA[ty+32][kk], a3=lA[ty+48][kk];
      float b0=lB[tx][kk], b1=lB[tx+16][kk], b2=lB[tx+32][kk], b3=lB[tx+48][kk];
      acc[0][0]+=a0*b0; acc[0][1]+=a0*b1; acc[0][2]+=a0*b2; acc[0][3]+=a0*b3;
      acc[1][0]+=a1*b0; acc[1][1]+=a1*b1; acc[1][2]+=a1*b2; acc[1][3]+=a1*b3;
      acc[2][0]+=a2*b0; acc[2][1]+=a2*b1; acc[2][2]+=a2*b2; acc[2][3]+=a2*b3;
      acc[3][0]+=a3*b0; acc[3][1]+=a3*b1; acc[3][2]+=a3*b2; acc[3][3]+=a3*b3;
    }
  }
  const float BNS = 0.99995000374968755f;
  #pragma unroll
  for (int j=0;j<4;j++){
    int gn = n0 + tx + 16*j;
    if (gn >= Ncol) continue;
    float bi = bias[gn];
    float gs = gam[gn]*BNS, be = bet[gn];
    #pragma unroll
    for (int i=0;i<4;i++){
      int gm = m0 + ty + 16*i;
      if (gm >= M) continue;
      float v = acc[i][j] + bi;
      v = v*gs + be; v = v > 0.f ? v : expm1f(v);
      out1[(size_t)gm*ldc + gn] = v;
      out2[(size_t)gm*ldc + gn] = v;
    }
  }
}

// ---------------- CSR build --------------------------------------------------
__global__ void csr_cnt_k(const int* __restrict__ key, int* __restrict__ cnt){
  int e = blockIdx.x*256 + threadIdx.x;
  if (e < NE) atomicAdd(&cnt[key[e]], 1);
}
__global__ __launch_bounds__(256)
void csr_scan_k(const int* __restrict__ cnt, int* __restrict__ rowptr, int* __restrict__ cursor){
  __shared__ int part[256];
  int t = threadIdx.x;
  int base = t*24;
  int loc[24]; int s=0;
  #pragma unroll
  for (int u=0;u<24;u++){
    int idx = base+u;
    int v = (idx<NN) ? cnt[idx] : 0;
    loc[u] = s; s += v;
  }
  part[t] = s;
  __syncthreads();
  if (t==0){
    int run=0;
    for (int u=0;u<256;u++){ int tmp=part[u]; part[u]=run; run+=tmp; }
  }
  __syncthreads();
  int off = part[t];
  #pragma unroll
  for (int u=0;u<24;u++){
    int idx = base+u;
    if (idx<NN){ rowptr[idx]=off+loc[u]; cursor[idx]=off+loc[u]; }
  }
  if (t==255) rowptr[NN] = off + s;
}
__global__ void csr_fill_k(const int* __restrict__ key, int* __restrict__ cursor,
                           int* __restrict__ elist){
  int e = blockIdx.x*256 + threadIdx.x;
  if (e < NE){ int pos = atomicAdd(&cursor[key[e]], 1); elist[pos] = e; }
}

// ---------------- fused per-node attention (dst-CSR, batched 2 encodes) -----
__global__ __launch_bounds__(256)
void attn_k(double* __restrict__ QKVS, const int* __restrict__ rowptr,
            const int* __restrict__ elist, const int* __restrict__ src,
            double* __restrict__ alpha)
{
  __shared__ double lg[4][128];
  const int w = threadIdx.x >> 6;
  const int node = blockIdx.x*4 + w;
  if (node >= 2*NN) return;
  const int base = (node < NN) ? 0 : NN;
  const int aoff = (node < NN) ? 0 : NE;
  const int cn = node - base;
  const int lane = threadIdx.x & 63;
  const int e0 = rowptr[cn], e1 = rowptr[cn+1];
  const int deg = e1 - e0;
  if (deg <= 0) return;
  const double SC = 0.088388347648318447; // 1/sqrt(128)
  const double* q = QKVS + (size_t)node*512;
  double q0 = q[lane], q1 = q[lane+64];

  if (deg <= 128){
    double m = -1.0e300;
    for (int i=0;i<deg;i++){
      const double* k = QKVS + (size_t)(src[elist[e0+i]] + base)*512 + 128;
      double p = q0*k[lane] + q1*k[lane+64];
      #pragma unroll
      for (int off=32; off; off>>=1) p += __shfl_xor(p, off);
      p *= SC;
      if (lane==0) lg[w][i] = p;
      m = fmax(m, p);
    }
    double S = 0.0;
    for (int i=0;i<deg;i++){
      double ex = exp(lg[w][i] - m);
      if (lane==0) lg[w][i] = ex;
      S += ex;
    }
    double inv = 1.0 / S;
    double o0 = QKVS[(size_t)node*512 + 384 + lane];
    double o1 = QKVS[(size_t)node*512 + 448 + lane];
    for (int i=0;i<deg;i++){
      int e = elist[e0+i];
      double a = lg[w][i] * inv;
      const double* v = QKVS + (size_t)(src[e] + base)*512 + 256;
      o0 = fma(a, v[lane],    o0);
      o1 = fma(a, v[lane+64], o1);
      if (lane==0) alpha[aoff + e] = a;
    }
    QKVS[(size_t)node*512 + 384 + lane] = o0;
    QKVS[(size_t)node*512 + 448 + lane] = o1;
  } else {
    double m = -1.0e300;
    for (int i=0;i<deg;i++){
      const double* k = QKVS + (size_t)(src[elist[e0+i]] + base)*512 + 128;
      double p = q0*k[lane] + q1*k[lane+64];
      #pragma unroll
      for (int off=32; off; off>>=1) p += __shfl_xor(p, off);
      m = fmax(m, p*SC);
    }
    double S = 0.0;
    for (int i=0;i<deg;i++){
      const double* k = QKVS + (size_t)(src[elist[e0+i]] + base)*512 + 128;
      double p = q0*k[lane] + q1*k[lane+64];
      #pragma unroll
      for (int off=32; off; off>>=1) p += __shfl_xor(p, off);
      S += exp(p*SC - m);
    }
    double inv = 1.0 / S;
    double o0 = QKVS[(size_t)node*512 + 384 + lane];
    double o1 = QKVS[(size_t)node*512 + 448 + lane];
    for (int i=0;i<deg;i++){
      int e = elist[e0+i];
      const double* k = QKVS + (size_t)(src[e] + base)*512 + 128;
      double p = q0*k[lane] + q1*k[lane+64];
      #pragma unroll
      for (int off=32; off; off>>=1) p += __shfl_xor(p, off);
      double a = exp(p*SC - m) * inv;
      const double* v = QKVS + (size_t)(src[e] + base)*512 + 256;
      o0 = fma(a, v[lane],    o0);
      o1 = fma(a, v[lane+64], o1);
      if (lane==0) alpha[aoff + e] = a;
    }
    QKVS[(size_t)node*512 + 384 + lane] = o0;
    QKVS[(size_t)node*512 + 448 + lane] = o1;
  }
}

// ---------------- fused spmm over src-CSR (both graphs, batched) ------------
__global__ __launch_bounds__(256)
void spmm_csr_k(const double* __restrict__ QK1, const double* __restrict__ QK2,
                const int* __restrict__ rpSA, const int* __restrict__ elSA,
                const int* __restrict__ dstA, const double* __restrict__ aA,
                const int* __restrict__ rpSP, const int* __restrict__ elSP,
                const int* __restrict__ dstP, const double* __restrict__ aP,
                double* __restrict__ out, int ldo, int offo, int dorelu)
{
  const int node = blockIdx.x*4 + (threadIdx.x>>6);
  if (node >= 2*NN) return;
  const int base = (node < NN) ? 0 : NN;
  const int aoff = (node < NN) ? 0 : NE;
  const int cn = node - base;
  const int lane = threadIdx.x & 63;
  double a0 = 0.0, a1 = 0.0;
  for (int idx = rpSA[cn]; idx < rpSA[cn+1]; ++idx){
    int e = elSA[idx]; int d = dstA[e];
    if (d != cn){
      double wgt = 0.5 * aA[aoff + e];
      const double* o = QK1 + (size_t)(d + base)*512 + 384;
      a0 = fma(wgt, o[lane],    a0);
      a1 = fma(wgt, o[lane+64], a1);
    }
  }
  for (int idx = rpSP[cn]; idx < rpSP[cn+1]; ++idx){
    int e = elSP[idx]; int d = dstP[e];
    if (d != cn){
      double wgt = 0.5 * aP[aoff + e];
      const double* o = QK2 + (size_t)(d + base)*512 + 384;
      a0 = fma(wgt, o[lane],    a0);
      a1 = fma(wgt, o[lane+64], a1);
    }
  }
  if (dorelu){ a0 = fmax(a0, 0.0); a1 = fmax(a1, 0.0); }
  out[(size_t)node*ldo + offo + lane]      = a0;
  out[(size_t)node*ldo + offo + 64 + lane] = a1;
}

__global__ void att_scatter_k(const int* __restrict__ src, const int* __restrict__ dst,
                              const double* __restrict__ alpha, float* __restrict__ att)
{
  int e = blockIdx.x*256 + threadIdx.x;
  if (e >= NE) return;
  int s = src[e], d = dst[e];
  if (s == d) return;
  atomicAdd(&att[(size_t)s*NN + d], (float)alpha[e]);
}

// ---------------- MFMA bf16 2-split distance + fused per-tile top-12 --------
__global__ __launch_bounds__(256)
void distmf_k(const unsigned short* __restrict__ zXh, const unsigned short* __restrict__ zXl,
              const unsigned short* __restrict__ zNh, const unsigned short* __restrict__ zNl,
              const float* __restrict__ sxA, const float* __restrict__ syA,
              const float* __restrict__ cjA,
              float* __restrict__ candV, int* __restrict__ candI)
{
  __shared__ __align__(16) char smem[40960 + 1536];
  typedef unsigned short u16;
  u16 (*lAh)[40] = (u16(*)[40])(smem);
  u16 (*lAl)[40] = (u16(*)[40])(smem + 10240);
  u16 (*lBh)[40] = (u16(*)[40])(smem + 20480);
  u16 (*lBl)[40] = (u16(*)[40])(smem + 30720);
  float (*stile)[67] = (float(*)[67])(smem);     // overlay after K loop
  float* sSx = (float*)(smem + 40960);
  float* sSy = sSx + 128;
  float* sC  = sSy + 128;

  const int tid = threadIdx.x;
  const int m0 = blockIdx.y * 128;
  const int n0 = blockIdx.x * 128;
  const int lane = tid & 63;
  const int wave = tid >> 6;
  const int wm = wave >> 1, wn = wave & 1;
  const int lr = lane & 15;
  const int lk = (lane >> 4) * 8;

  if (tid < 128){
    int jg = n0 + tid;
    if (jg < NN){ sSx[tid]=sxA[jg]; sSy[tid]=syA[jg]; sC[tid]=cjA[jg]; }
    else        { sSx[tid]=0.f; sSy[tid]=0.f; sC[tid]=-3e38f; }
  }

  f32x4 acc[4][4];
  #pragma unroll
  for (int i=0;i<4;i++)
    #pragma unroll
    for (int j=0;j<4;j++) acc[i][j] = (f32x4){0.f,0.f,0.f,0.f};

  for (int kt = 0; kt < 8; kt++){
    const int k0 = kt << 5;
    __syncthreads();
    #pragma unroll
    for (int c=0;c<4;c++){
      int lin = tid + c*256;
      int row = lin >> 3;
      int kc = (lin & 7) << 2;
      int gm = m0 + row, gn = n0 + row;
      ushort4 vh = {0,0,0,0}, vl = {0,0,0,0}, wh = {0,0,0,0}, wl = {0,0,0,0};
      if (gm < NN){
        vh = *(const ushort4*)(zXh + (size_t)gm*256 + k0 + kc);
        vl = *(const ushort4*)(zXl + (size_t)gm*256 + k0 + kc);
      }
      if (gn < NN){
        wh = *(const ushort4*)(zNh + (size_t)gn*256 + k0 + kc);
        wl = *(const ushort4*)(zNl + (size_t)gn*256 + k0 + kc);
      }
      *(ushort4*)&lAh[row][kc] = vh;
      *(ushort4*)&lAl[row][kc] = vl;
      *(ushort4*)&lBh[row][kc] = wh;
      *(ushort4*)&lBl[row][kc] = wl;
    }
    __syncthreads();
    short8 ah[4], al[4];
    #pragma unroll
    for (int fm=0; fm<4; fm++){
      ah[fm] = *(const short8*)&lAh[wm*64 + fm*16 + lr][lk];
      al[fm] = *(const short8*)&lAl[wm*64 + fm*16 + lr][lk];
    }
    #pragma unroll
    for (int fn=0; fn<4; fn++){
      short8 bh = *(const short8*)&lBh[wn*64 + fn*16 + lr][lk];
      short8 bl = *(const short8*)&lBl[wn*64 + fn*16 + lr][lk];
      #pragma unroll
      for (int fm=0; fm<4; fm++){
        acc[fm][fn] = __builtin_amdgcn_mfma_f32_16x16x32_bf16(ah[fm], bh, acc[fm][fn], 0,0,0);
        acc[fm][fn] = __builtin_amdgcn_mfma_f32_16x16x32_bf16(ah[fm], bl, acc[fm][fn], 0,0,0);
        acc[fm][fn] = __builtin_amdgcn_mfma_f32_16x16x32_bf16(al[fm], bh, acc[fm][fn], 0,0,0);
      }
    }
  }

  float tv[NCAND]; int ti[NCAND];
  #pragma unroll
  for (int p=0;p<NCAND;p++){ tv[p] = -3.4e38f; ti[p] = -1; }
  const int gi = m0 + tid;
  float sxi = 0.f, syi = 0.f;
  if (tid < 128 && gi < NN){ sxi = sxA[gi]; syi = syA[gi]; }

  for (int jh = 0; jh < 2; jh++){
    __syncthreads();
    if (wn == jh){
      #pragma unroll
      for (int fm=0;fm<4;fm++){
        #pragma unroll
        for (int fn=0;fn<4;fn++){
          int lrow = wm*64 + fm*16 + ((lane>>4)<<2);
          int lcol = fn*16 + lr;
          #pragma unroll
          for (int r=0;r<4;r++)
            stile[lrow + r][lcol] = acc[fm][fn][r];
        }
      }
    }
    __syncthreads();
    if (tid < 128 && gi < NN){
      #pragma unroll 1
      for (int jj=0; jj<64; jj++){
        int j = jh*64 + jj;
        float s = 2.f*stile[tid][jj] + 2.f*(sxi*sSx[j] + syi*sSy[j]) + sC[j];
        if (s > tv[NCAND-1]){
          bool g[NCAND];
          #pragma unroll
          for (int p=0;p<NCAND;p++) g[p] = s > tv[p];
          #pragma unroll
          for (int p=NCAND-1;p>0;--p) if (g[p-1]){ tv[p]=tv[p-1]; ti[p]=ti[p-1]; }
          #pragma unroll
          for (int p=0;p<NCAND;p++){ bool pl = g[p] && (p==0 || !g[p-1]); if (pl){ tv[p]=s; ti[p]=n0+j; } }
        }
      }
    }
  }
  if (tid < 128 && gi < NN){
    size_t base = ((size_t)gi*NTILE + blockIdx.x)*NCAND;
    #pragma unroll
    for (int p=0;p<NCAND;p++){ candV[base+p]=tv[p]; candI[base+p]=ti[p]; }
  }
}

// ---------------- merge: 32x block-argmax prefilter -> f64 rescore -> top-9 -
__global__ __launch_bounds__(256)
void merge64_k(const float* __restrict__ candV, const int* __restrict__ candI,
               const double* __restrict__ Z, const double* __restrict__ Znb,
               const double* __restrict__ sx64, const double* __restrict__ sy64,
               double* __restrict__ wgt9, int* __restrict__ idx9)
{
  __shared__ double zi[256];
  __shared__ int    fjS[TCAND];
  __shared__ float  wbv[4];
  __shared__ int    wbc[4];
  __shared__ int    chosen;
  __shared__ int    pj[PRE];
  __shared__ double ps[PRE];

  const int i = blockIdx.x;
  const int t = threadIdx.x;
  const int lane = t & 63, wv = t >> 6;

  zi[t] = Z[(size_t)i*256 + t];

  float v0 = -3.4e38f, v1 = -3.4e38f, v2 = -3.4e38f;
  const int c0 = t, c1 = t + 256, c2 = t + 512;
  {
    float vv = candV[(size_t)i*TCAND + c0];
    int jj = candI[(size_t)i*TCAND + c0];
    fjS[c0] = jj;
    if (jj >= 0) v0 = vv;
  }
  if (c1 < TCAND){
    float vv = candV[(size_t)i*TCAND + c1];
    int jj = candI[(size_t)i*TCAND + c1];
    fjS[c1] = jj;
    if (jj >= 0) v1 = vv;
  }
  if (c2 < TCAND){
    float vv = candV[(size_t)i*TCAND + c2];
    int jj = candI[(size_t)i*TCAND + c2];
    fjS[c2] = jj;
    if (jj >= 0) v2 = vv;
  }
  __syncthreads();

  for (int it = 0; it < PRE; it++){
    float bv = v0; int bc = c0;
    if (v1 > bv || (v1 == bv && c1 < bc)){ bv = v1; bc = c1; }
    if (v2 > bv || (v2 == bv && c2 < bc)){ bv = v2; bc = c2; }
    #pragma unroll
    for (int off = 32; off; off >>= 1){
      float ov = __shfl_xor(bv, off);
      int   oc = __shfl_xor(bc, off);
      if (ov > bv || (ov == bv && oc < bc)){ bv = ov; bc = oc; }
    }
    if (lane == 0){ wbv[wv] = bv; wbc[wv] = bc; }
    __syncthreads();
    if (t == 0){
      float gb = wbv[0]; int gc = wbc[0];
      #pragma unroll
      for (int w2 = 1; w2 < 4; w2++)
        if (wbv[w2] > gb || (wbv[w2] == gb && wbc[w2] < gc)){ gb = wbv[w2]; gc = wbc[w2]; }
      chosen = gc;
      pj[it] = fjS[gc];
    }
    __syncthreads();
    int gc = chosen;
    if (c0 == gc) v0 = -3.4e38f;
    if (c1 == gc) v1 = -3.4e38f;
    if (c2 == gc) v2 = -3.4e38f;
  }

  const double sxi = sx64[i], syi = sy64[i];
  for (int c = wv; c < PRE; c += 4){
    int j = pj[c];
    const double* zj = Znb + (size_t)j*256;
    double p = 0.0;
    #pragma unroll
    for (int u = 0; u < 4; u++){
      double b = zj[lane + 64*u];
      double a = zi[lane + 64*u];
      p = fma(2.0*a - b, b, p);     // += 2ab - b^2
    }
    #pragma unroll
    for (int off = 32; off; off >>= 1) p += __shfl_xor(p, off);
    double sxj = sx64[j], syj = sy64[j];
    double s = p + 2.0*(sxi*sxj + syi*syj) - (sxj*sxj + syj*syj);
    if (lane == 0) ps[c] = s;
  }
  __syncthreads();

  if (t == 0){
    double tv9[9]; int ti9[9];
    #pragma unroll
    for (int p = 0; p < 9; p++){ tv9[p] = -1.0e301; ti9[p] = 0x7FFFFFFF; }
    for (int c = 0; c < PRE; c++){
      double s = ps[c]; int j = pj[c];
      if (!((s > tv9[8]) || (s == tv9[8] && j < ti9[8]))) continue;
      int p = 8;
      while (p > 0 && ((s > tv9[p-1]) || (s == tv9[p-1] && j < ti9[p-1]))){
        tv9[p] = tv9[p-1]; ti9[p] = ti9[p-1]; --p;
      }
      tv9[p] = s; ti9[p] = j;
    }
    double m = tv9[0], e[9], S = 0.0;
    #pragma unroll
    for (int k = 0; k < 9; k++){ e[k] = exp(tv9[k] - m); S += e[k]; }
    #pragma unroll
    for (int k = 0; k < 9; k++){
      wgt9[(size_t)i*9 + k] = e[k] / S;
      idx9[(size_t)i*9 + k] = ti9[k];
    }
  }
}

// ---------------- znb prep + casts ------------------------------------------
__global__ __launch_bounds__(256)
void znbprep_k(const double* __restrict__ znb, const double* __restrict__ ssq64,
               float* __restrict__ cjA)
{
  __shared__ double red[256];
  int i = blockIdx.x, d = threadIdx.x;
  double v = znb[(size_t)i*256 + d];
  red[d] = v*v;
  __syncthreads();
  for (int s=128; s; s>>=1){ if (d<s) red[d]+=red[d+s]; __syncthreads(); }
  if (d==0) cjA[i] = -(float)(red[0] + ssq64[i]);
}
__global__ void featout_k(const double* __restrict__ z, float* __restrict__ o){
  int t = blockIdx.x*256+threadIdx.x;
  if (t < NN*128){ int i=t>>7, d=t&127; o[t] = (float)z[(size_t)i*256 + d]; }
}

__global__ __launch_bounds__(256)
void zout_k(const double* __restrict__ Z, const double* __restrict__ Znb,
            const int* __restrict__ idx9, const double* __restrict__ wgt9,
            float* __restrict__ zoOut, float* __restrict__ zoF32, float* __restrict__ x1)
{
  int i = blockIdx.x; int d = threadIdx.x;
  double a = Z[(size_t)i*256 + d];
  #pragma unroll
  for (int k=0;k<9;k++){
    int j = idx9[(size_t)i*9+k];
    double w = wgt9[(size_t)i*9+k];
    double t = w * Znb[(size_t)j*256 + d];
    a += t;
    x1[((size_t)i*9+k)*256 + d] = (float)t;
  }
  float af = (float)a;
  zoOut[(size_t)i*256+d] = af;
  zoF32[(size_t)i*256+d] = af;
}

__global__ __launch_bounds__(256)
void q_k(const float* __restrict__ zoF, const float* __restrict__ clus, float* __restrict__ qB)
{
  __shared__ float wred[10][4];
  __shared__ float qs[10];
  int i = blockIdx.x, d = threadIdx.x;
  int lane = d & 63, wv = d >> 6;
  float zo = zoF[(size_t)i*256 + d];
  #pragma unroll
  for (int c=0;c<10;c++){
    float df = zo - clus[(size_t)c*256 + d];
    float p = df*df;
    #pragma unroll
    for (int off=32; off; off>>=1) p += __shfl_down(p, off);
    if (lane == 0) wred[c][wv] = p;
  }
  __syncthreads();
  if (d < 10){
    float d2 = wred[d][0]+wred[d][1]+wred[d][2]+wred[d][3];
    qs[d] = 1.f/(1.f + d2);
  }
  __syncthreads();
  if (d < 10){
    float s = 0.f;
    #pragma unroll
    for (int c=0;c<10;c++) s += qs[c];
    qB[(size_t)i*10 + d] = qs[d]/s;
  }
}

// ---------------- host ------------------------------------------------------
extern "C" void kernel_launch(void* const* d_in, const int* in_sizes, int n_in,
                              void* d_out, int out_size, void* d_ws, size_t ws_size,
                              hipStream_t stream)
{
  (void)in_sizes; (void)n_in; (void)out_size; (void)ws_size;
  const float* x    = (const float*)d_in[0];
  const float* xnb  = (const float*)d_in[1];
  const float* spat = (const float*)d_in[2];
  const int*   adj  = (const int*)d_in[3];
  const int*   adjp = (const int*)d_in[4];
  const float* W1   = (const float*)d_in[5];
  const float* b1   = (const float*)d_in[6];
  const float* g1   = (const float*)d_in[7];
  const float* be1  = (const float*)d_in[8];
  const float* W2   = (const float*)d_in[9];
  const float* b2   = (const float*)d_in[10];
  const float* g2   = (const float*)d_in[11];
  const float* be2  = (const float*)d_in[12];
  const float* Wq   = (const float*)d_in[13];
  const float* Wk   = (const float*)d_in[14];
  const float* Wv   = (const float*)d_in[15];
  const float* Wsm  = (const float*)d_in[16];
  const float* bq   = (const float*)d_in[17];
  const float* bk   = (const float*)d_in[18];
  const float* bv   = (const float*)d_in[19];
  const float* bs   = (const float*)d_in[20];
  const float* decW = (const float*)d_in[21];
  const float* decb = (const float*)d_in[22];
  const float* decg = (const float*)d_in[23];
  const float* decbe= (const float*)d_in[24];
  const float* clus = (const float*)d_in[25];
  float* outF = (float*)d_out;
  const int* srcA = adj,  *dstA = adj + NE;
  const int* srcP = adjp, *dstP = adjp + NE;

  char* wsb = (char*)d_ws;
  size_t off = 0;
  auto alloc = [&](size_t bytes)->char*{
    char* p = wsb + off;
    off = (off + bytes + 255) & ~(size_t)255;
    return p;
  };
  double* W1t  = (double*)alloc(768000*8);
  double* W2t  = (double*)alloc(32768*8);
  double* Bct  = (double*)alloc(196608*8);
  float*  Dt   = (float*) alloc(768000*4);
  double* bcat = (double*)alloc(1536*8);
  double* sx64 = (double*)alloc(NN*8);
  double* sy64 = (double*)alloc(NN*8);
  double* ssq64= (double*)alloc(NN*8);
  float*  sx32 = (float*) alloc(NN*4);
  float*  sy32 = (float*) alloc(NN*4);
  double* b1c  = (double*)alloc(256*8);
  double* b2c  = (double*)alloc(128*8);
  double* H1   = (double*)alloc((size_t)2*NN*256*8);
  double* zAll = (double*)alloc((size_t)2*NN*256*8);
  double* hcur = (double*)alloc((size_t)2*NN*128*8);
  double* QK1  = (double*)alloc((size_t)2*NN*512*8);
  double* QK2  = (double*)alloc((size_t)2*NN*512*8);
  double* alphaA=(double*)alloc((size_t)2*NE*8);
  double* alphaP=(double*)alloc((size_t)2*NE*8);
  double* part = (double*)alloc((size_t)4*2*NN*256*8);   // split-K partials (98 MB)
  // CSRs
  int* rpDA = (int*)alloc((NN+1)*4);
  int* rpDP = (int*)alloc((NN+1)*4);
  int* rpSA = (int*)alloc((NN+1)*4);
  int* rpSP = (int*)alloc((NN+1)*4);
  int* curDA= (int*)alloc(NN*4);
  int* curDP= (int*)alloc(NN*4);
  int* curSA= (int*)alloc(NN*4);
  int* curSP= (int*)alloc(NN*4);
  int* elDA = (int*)alloc(NE*4);
  int* elDP = (int*)alloc(NE*4);
  int* elSA = (int*)alloc(NE*4);
  int* elSP = (int*)alloc(NE*4);
  unsigned short* zXh = (unsigned short*)alloc((size_t)NN*256*2);
  unsigned short* zXl = (unsigned short*)alloc((size_t)NN*256*2);
  unsigned short* zNh = (unsigned short*)alloc((size_t)NN*256*2);
  unsigned short* zNl = (unsigned short*)alloc((size_t)NN*256*2);
  float*  cjA  = (float*) alloc(NN*4);
  float*  candV= (float*) alloc((size_t)NN*TCAND*4);
  int*    candI= (int*)   alloc((size_t)NN*TCAND*4);
  int*    idx9 = (int*)   alloc((size_t)NN*9*4);
  double* wgt9 = (double*)alloc((size_t)NN*9*8);
  float*  zoF32= (float*) alloc((size_t)NN*256*4);

  double* zX64  = zAll;
  double* zNB64 = zAll + (size_t)NN*256;

  prep_k<<<6926, 256, 0, stream>>>(W1, W2, Wq, Wk, Wv, Wsm, bq, bk, bv, bs, decW, spat,
                                   W1t, W2t, Bct, Dt, bcat,
                                   sx64, sy64, ssq64, sx32, sy32);
  castup_k<<<1, 256, 0, stream>>>(b1, b1c, 256);
  castup_k<<<1, 256, 0, stream>>>(b2, b2c, 128);

  // CSR build (4 CSRs)
  hipMemsetAsync(curDA, 0, NN*4, stream);
  hipMemsetAsync(curDP, 0, NN*4, stream);
  hipMemsetAsync(curSA, 0, NN*4, stream);
  hipMemsetAsync(curSP, 0, NN*4, stream);
  csr_cnt_k<<<375, 256, 0, stream>>>(dstA, curDA);
  csr_cnt_k<<<375, 256, 0, stream>>>(dstP, curDP);
  csr_cnt_k<<<375, 256, 0, stream>>>(srcA, curSA);
  csr_cnt_k<<<375, 256, 0, stream>>>(srcP, curSP);
  csr_scan_k<<<1, 256, 0, stream>>>(curDA, rpDA, curDA);
  csr_scan_k<<<1, 256, 0, stream>>>(curDP, rpDP, curDP);
  csr_scan_k<<<1, 256, 0, stream>>>(curSA, rpSA, curSA);
  csr_scan_k<<<1, 256, 0, stream>>>(curSP, rpSP, curSP);
  csr_fill_k<<<375, 256, 0, stream>>>(dstA, curDA, elDA);
  csr_fill_k<<<375, 256, 0, stream>>>(dstP, curDP, elDP);
  csr_fill_k<<<375, 256, 0, stream>>>(srcA, curSA, elSA);
  csr_fill_k<<<375, 256, 0, stream>>>(srcP, curSP, elSP);

  const int M2 = 2*NN;   // 12000 batched rows

  // batched encoder GEMM 1: A rows [0,6000) from x, [6000,12000) from xnb
  gemm64s_k<float><<<dim3(4,188,4), 256, 0, stream>>>(x, xnb, NN, KDIN, W1t, KDIN,
                                                      M2, KDIN, 768, 256, part);
  epi64_k<<<(M2*256+255)/256, 256, 0, stream>>>(part, 4, (size_t)M2*256,
                                                M2, 256, b1c, g1, be1, H1, 256);
  // batched encoder GEMM 2
  gemm64s_k<double><<<dim3(2,188,4), 256, 0, stream>>>(H1, H1, M2, 256, W2t, 256,
                                                       M2, 256, 64, 128, part);
  epi64_k<<<(M2*128+255)/256, 256, 0, stream>>>(part, 4, (size_t)M2*128,
                                                M2, 128, b2c, g2, be2, zAll, 256);

  const double* hin = zAll; int ldh = 256;
  for (int l=0; l<3; l++){
    const double* Bh = Bct + (size_t)l*65536;
    const double* bc = bcat + l*512;
    if (l != 1){
      gemm64_k<0,double><<<dim3(8,188), 256, 0, stream>>>(hin, ldh, Bh, 128, M2, 128, 512,
                                                          QK1, 512, bc, nullptr, nullptr, QK2);
      attn_k<<<3000, 256, 0, stream>>>(QK1, rpDA, elDA, srcA, alphaA);
      attn_k<<<3000, 256, 0, stream>>>(QK2, rpDP, elDP, srcP, alphaP);
    } else {
      gemm64_k<0,double><<<dim3(8,188), 256, 0, stream>>>(hin, ldh, Bh, 128, M2, 128, 512,
                                                          QK1, 512, bc, nullptr, nullptr, nullptr);
      attn_k<<<3000, 256, 0, stream>>>(QK1, rpDA, elDA, srcA, alphaA);
      gemm64_k<0,double><<<dim3(8,188), 256, 0, stream>>>(QK1 + 384, 512, Bh, 128, M2, 128, 512,
                                                          QK2, 512, bc, nullptr, nullptr, nullptr);
      attn_k<<<3000, 256, 0, stream>>>(QK2, rpDP, elDP, srcP, alphaP);
    }
    if (l == 2){
      hipMemsetAsync(outF + (size_t)OFF_ATT, 0, (size_t)NN*NN*4, stream);
      att_scatter_k<<<375, 256, 0, stream>>>(srcP, dstP, alphaP, outF + (size_t)OFF_ATT);
    }
    if (l < 2){
      spmm_csr_k<<<3000, 256, 0, stream>>>(QK1, QK2, rpSA, elSA, dstA, alphaA,
                                           rpSP, elSP, dstP, alphaP, hcur, 128, 0, 1);
      hin = hcur; ldh = 128;
    } else {
      spmm_csr_k<<<3000, 256, 0, stream>>>(QK1, QK2, rpSA, elSA, dstA, alphaA,
                                           rpSP, elSP, dstP, alphaP, zAll, 256, 128, 0);
    }
  }

  splitz_k<<<6000, 256, 0, stream>>>(zX64,  zXh, zXl, NN*256);
  splitz_k<<<6000, 256, 0, stream>>>(zNB64, zNh, zNl, NN*256);
  znbprep_k<<<NN, 256, 0, stream>>>(zNB64, ssq64, cjA);
  distmf_k<<<dim3(NTILE,47), 256, 0, stream>>>(zXh, zXl, zNh, zNl,
                                               sx32, sy32, cjA, candV, candI);
  merge64_k<<<NN, 256, 0, stream>>>(candV, candI, zX64, zNB64, sx64, sy64, wgt9, idx9);

  zout_k<<<NN, 256, 0, stream>>>(zX64, zNB64, idx9, wgt9,
                                 outF + (size_t)OFF_ZOUT, zoF32, outF + (size_t)OFF_X1);
  gemm32d_k<<<dim3(47,94), 256, 0, stream>>>(zoF32, 256, Dt, 256, NN, 256, 3000,
                                             outF + (size_t)OFF_DE1, 3000, decb, decg, decbe,
                                             outF + (size_t)OFF_DE2);
  q_k<<<NN, 256, 0, stream>>>(zoF32, clus, outF + (size_t)OFF_Q);
  featout_k<<<3000, 256, 0, stream>>>(zX64, outF + (size_t)OFF_FEAT);
}

// Round 20
// 2605.293 us; speedup vs baseline: 1.1018x; 1.0202x over previous
//
#include <hip/hip_runtime.h>
#include <hip/hip_bf16.h>
#include <math.h>
#include <stdint.h>

#define NN 6000
#define NE 96000
#define KDIN 3000
#define NCAND 12            // candidates per 128-col tile
#define NTILE 47
#define TCAND (NCAND*NTILE) // 564 per row
#define PRE 32              // f64-rescored candidates per row

// output element offsets (d_out is FLOAT32)
#define OFF_ZOUT 0
#define OFF_DE1  1536000
#define OFF_Q    19536000
#define OFF_FEAT 19596000
#define OFF_DE2  20364000
#define OFF_X1   38364000
#define OFF_ATT  52188000

typedef __attribute__((ext_vector_type(8))) short short8;
typedef __attribute__((ext_vector_type(4))) float f32x4;

__device__ __forceinline__ unsigned short f2bf(float f){
  unsigned int u = __float_as_uint(f);
  u += 0x7FFFu + ((u >> 16) & 1u);
  return (unsigned short)(u >> 16);
}
__device__ __forceinline__ float bf2f(unsigned short h){
  return __uint_as_float(((unsigned int)h) << 16);
}
__device__ __forceinline__ void split2(float v, unsigned short &h, unsigned short &l){
  h = f2bf(v);
  l = f2bf(v - bf2f(h));
}

// ---------------- weight prep: transpose, cast to f64 -----------------------
__global__ void prep_k(const float* __restrict__ W1, const float* __restrict__ W2,
                       const float* __restrict__ Wq, const float* __restrict__ Wk,
                       const float* __restrict__ Wv, const float* __restrict__ Ws,
                       const float* __restrict__ bq, const float* __restrict__ bk,
                       const float* __restrict__ bv, const float* __restrict__ bs,
                       const float* __restrict__ decW, const float* __restrict__ spat,
                       double* __restrict__ W1t, double* __restrict__ W2t,
                       double* __restrict__ Bct,
                       unsigned short* __restrict__ DtH, unsigned short* __restrict__ DtL,
                       double* __restrict__ bcat,
                       double* __restrict__ sx64, double* __restrict__ sy64,
                       double* __restrict__ ssq64,
                       float* __restrict__ sx32, float* __restrict__ sy32)
{
  int t = blockIdx.x * 256 + threadIdx.x;
  if (t < 768000){
    int n = t / 3000, k = t % 3000;
    W1t[t] = (double)W1[(size_t)k * 256 + n]; return;
  }
  t -= 768000;
  if (t < 32768){
    int n = t / 256, k = t % 256;
    W2t[t] = (double)W2[(size_t)k * 128 + n]; return;
  }
  t -= 32768;
  if (t < 196608){
    int l = t / 65536; int rem = t % 65536;
    int n = rem / 128, k = rem % 128;
    int sel = n >> 7, nn = n & 127;
    const float* Wm = sel==0 ? Wq : sel==1 ? Wk : sel==2 ? Wv : Ws;
    Bct[t] = (double)Wm[((size_t)(l*128) + k) * 128 + nn]; return;
  }
  t -= 196608;
  if (t < 768000){
    int n = t / 256, k = t % 256;
    float v = decW[(size_t)k * 3000 + n];
    unsigned short h,l; split2(v,h,l);
    DtH[t]=h; DtL[t]=l; return;
  }
  t -= 768000;
  if (t < 1536){
    int l = t / 512, n = t % 512;
    int sel = n >> 7, nn = n & 127;
    const float* bm = sel==0 ? bq : sel==1 ? bk : sel==2 ? bv : bs;
    bcat[t] = (double)bm[l*128 + nn]; return;
  }
  t -= 1536;
  if (t < NN){
    float sx = spat[(size_t)t*2], sy = spat[(size_t)t*2+1];
    sx64[t]=(double)sx; sy64[t]=(double)sy;
    ssq64[t]=(double)sx*(double)sx + (double)sy*(double)sy;
    sx32[t]=sx; sy32[t]=sy; return;
  }
}

__global__ void castup_k(const float* __restrict__ s, double* __restrict__ d, int n){
  int t = blockIdx.x*256 + threadIdx.x;
  if (t < n) d[t] = (double)s[t];
}

// split f64 z -> bf16 hi/lo (via f32)
__global__ void splitz_k(const double* __restrict__ z64, unsigned short* __restrict__ zh,
                         unsigned short* __restrict__ zl, int n){
  int t = blockIdx.x*256 + threadIdx.x;
  if (t < n){
    float v = (float)z64[t];
    unsigned short h = f2bf(v);
    float r = v - bf2f(h);
    zh[t] = h; zl[t] = f2bf(r);
  }
}

// ---------------- f64 vector GEMM, NT, 64x64, BK=16, double2 LDS reads ------
template<int EPI, typename TA>
__global__ __launch_bounds__(256)
void gemm64_k(const TA* __restrict__ A, int lda,
              const double* __restrict__ Bt, int ldb,
              int M, int K, int Ncol,
              double* __restrict__ outF, int ldc,
              const double* __restrict__ bias,
              const float* __restrict__ gam, const float* __restrict__ bet,
              double* __restrict__ outF2)
{
  __shared__ double lA[64][18];
  __shared__ double lB[64][18];
  const int tid = threadIdx.x;
  const int m0 = blockIdx.y * 64;
  const int n0 = blockIdx.x * 64;
  const int tx = tid & 15;
  const int ty = tid >> 4;

  double acc[4][4];
  #pragma unroll
  for (int i=0;i<4;i++)
    #pragma unroll
    for (int j=0;j<4;j++) acc[i][j] = 0.0;

  const int nkt = (K + 15) >> 4;
  for (int kt = 0; kt < nkt; kt++){
    const int k0 = kt << 4;
    __syncthreads();
    #pragma unroll
    for (int c=0;c<4;c++){
      int lin = tid + c*256;
      int row = lin >> 4, col = lin & 15;
      int gm = m0 + row, gk = k0 + col;
      double va = 0.0, vb = 0.0;
      if (gm < M && gk < K)        va = (double)A [(size_t)gm*lda + gk];
      if (n0+row < Ncol && gk < K) vb = Bt[(size_t)(n0+row)*ldb + gk];
      lA[row][col] = va;
      lB[row][col] = vb;
    }
    __syncthreads();
    #pragma unroll 4
    for (int kk=0; kk<16; kk+=2){
      double2 A0 = *(const double2*)&lA[ty   ][kk];
      double2 A1 = *(const double2*)&lA[ty+16][kk];
      double2 A2 = *(const double2*)&lA[ty+32][kk];
      double2 A3 = *(const double2*)&lA[ty+48][kk];
      double2 B0 = *(const double2*)&lB[tx   ][kk];
      double2 B1 = *(const double2*)&lB[tx+16][kk];
      double2 B2 = *(const double2*)&lB[tx+32][kk];
      double2 B3 = *(const double2*)&lB[tx+48][kk];
      acc[0][0]+=A0.x*B0.x; acc[0][1]+=A0.x*B1.x; acc[0][2]+=A0.x*B2.x; acc[0][3]+=A0.x*B3.x;
      acc[1][0]+=A1.x*B0.x; acc[1][1]+=A1.x*B1.x; acc[1][2]+=A1.x*B2.x; acc[1][3]+=A1.x*B3.x;
      acc[2][0]+=A2.x*B0.x; acc[2][1]+=A2.x*B1.x; acc[2][2]+=A2.x*B2.x; acc[2][3]+=A2.x*B3.x;
      acc[3][0]+=A3.x*B0.x; acc[3][1]+=A3.x*B1.x; acc[3][2]+=A3.x*B2.x; acc[3][3]+=A3.x*B3.x;
      acc[0][0]+=A0.y*B0.y; acc[0][1]+=A0.y*B1.y; acc[0][2]+=A0.y*B2.y; acc[0][3]+=A0.y*B3.y;
      acc[1][0]+=A1.y*B0.y; acc[1][1]+=A1.y*B1.y; acc[1][2]+=A1.y*B2.y; acc[1][3]+=A1.y*B3.y;
      acc[2][0]+=A2.y*B0.y; acc[2][1]+=A2.y*B1.y; acc[2][2]+=A2.y*B2.y; acc[2][3]+=A2.y*B3.y;
      acc[3][0]+=A3.y*B0.y; acc[3][1]+=A3.y*B1.y; acc[3][2]+=A3.y*B2.y; acc[3][3]+=A3.y*B3.y;
    }
  }
  #pragma unroll
  for (int j=0;j<4;j++){
    int gn = n0 + tx + 16*j;
    if (gn >= Ncol) continue;
    double bi = bias[gn];
    #pragma unroll
    for (int i=0;i<4;i++){
      int gm = m0 + ty + 16*i;
      if (gm >= M) continue;
      double v = acc[i][j] + bi;
      outF[(size_t)gm*ldc + gn] = v;
      if (outF2) outF2[(size_t)gm*ldc + gn] = v;
    }
  }
}

// ---------------- split-K f64 GEMM (BK=16), two A sources -------------------
template<typename TA>
__global__ __launch_bounds__(256)
void gemm64s_k(const TA* __restrict__ A, const TA* __restrict__ A2, int M1, int lda,
               const double* __restrict__ Bt, int ldb,
               int M, int K, int kchunk, int Ncol,
               double* __restrict__ part)   // [z][M*Ncol]
{
  __shared__ double lA[64][18];
  __shared__ double lB[64][18];
  const int tid = threadIdx.x;
  const int m0 = blockIdx.y * 64;
  const int n0 = blockIdx.x * 64;
  const int tx = tid & 15;
  const int ty = tid >> 4;
  const int kbeg = blockIdx.z * kchunk;
  const int kend = min(K, kbeg + kchunk);
  double* dst = part + (size_t)blockIdx.z * M * Ncol;

  double acc[4][4];
  #pragma unroll
  for (int i=0;i<4;i++)
    #pragma unroll
    for (int j=0;j<4;j++) acc[i][j] = 0.0;

  const int nkt = (kend - kbeg + 15) >> 4;
  for (int kt = 0; kt < nkt; kt++){
    const int k0 = kbeg + (kt << 4);
    __syncthreads();
    #pragma unroll
    for (int c=0;c<4;c++){
      int lin = tid + c*256;
      int row = lin >> 4, col = lin & 15;
      int gm = m0 + row, gk = k0 + col;
      double va = 0.0, vb = 0.0;
      if (gm < M && gk < kend){
        va = (gm < M1) ? (double)A[(size_t)gm*lda + gk]
                       : (double)A2[(size_t)(gm-M1)*lda + gk];
      }
      if (n0+row < Ncol && gk < kend) vb = Bt[(size_t)(n0+row)*ldb + gk];
      lA[row][col] = va;
      lB[row][col] = vb;
    }
    __syncthreads();
    #pragma unroll 4
    for (int kk=0; kk<16; kk+=2){
      double2 A0 = *(const double2*)&lA[ty   ][kk];
      double2 A1 = *(const double2*)&lA[ty+16][kk];
      double2 A2v = *(const double2*)&lA[ty+32][kk];
      double2 A3 = *(const double2*)&lA[ty+48][kk];
      double2 B0 = *(const double2*)&lB[tx   ][kk];
      double2 B1 = *(const double2*)&lB[tx+16][kk];
      double2 B2 = *(const double2*)&lB[tx+32][kk];
      double2 B3 = *(const double2*)&lB[tx+48][kk];
      acc[0][0]+=A0.x*B0.x; acc[0][1]+=A0.x*B1.x; acc[0][2]+=A0.x*B2.x; acc[0][3]+=A0.x*B3.x;
      acc[1][0]+=A1.x*B0.x; acc[1][1]+=A1.x*B1.x; acc[1][2]+=A1.x*B2.x; acc[1][3]+=A1.x*B3.x;
      acc[2][0]+=A2v.x*B0.x; acc[2][1]+=A2v.x*B1.x; acc[2][2]+=A2v.x*B2.x; acc[2][3]+=A2v.x*B3.x;
      acc[3][0]+=A3.x*B0.x; acc[3][1]+=A3.x*B1.x; acc[3][2]+=A3.x*B2.x; acc[3][3]+=A3.x*B3.x;
      acc[0][0]+=A0.y*B0.y; acc[0][1]+=A0.y*B1.y; acc[0][2]+=A0.y*B2.y; acc[0][3]+=A0.y*B3.y;
      acc[1][0]+=A1.y*B0.y; acc[1][1]+=A1.y*B1.y; acc[1][2]+=A1.y*B2.y; acc[1][3]+=A1.y*B3.y;
      acc[2][0]+=A2v.y*B0.y; acc[2][1]+=A2v.y*B1.y; acc[2][2]+=A2v.y*B2.y; acc[2][3]+=A2v.y*B3.y;
      acc[3][0]+=A3.y*B0.y; acc[3][1]+=A3.y*B1.y; acc[3][2]+=A3.y*B2.y; acc[3][3]+=A3.y*B3.y;
    }
  }
  #pragma unroll
  for (int j=0;j<4;j++){
    int gn = n0 + tx + 16*j;
    if (gn >= Ncol) continue;
    #pragma unroll
    for (int i=0;i<4;i++){
      int gm = m0 + ty + 16*i;
      if (gm >= M) continue;
      dst[(size_t)gm*Ncol + gn] = acc[i][j];
    }
  }
}

// reduce partials + bias + BN + ELU -> out (f64)
__global__ void epi64_k(const double* __restrict__ part, int nsplit, size_t pstride,
                        int M, int Ncol, const double* __restrict__ bias,
                        const float* __restrict__ gam, const float* __restrict__ bet,
                        double* __restrict__ out, int ldo)
{
  int t = blockIdx.x*256 + threadIdx.x;
  if (t >= M*Ncol) return;
  int gm = t / Ncol, gn = t - gm*Ncol;
  double v = 0.0;
  for (int s=0; s<nsplit; s++) v += part[(size_t)s*pstride + t];
  const double BNS = 0.99995000374968755261;
  v += bias[gn];
  v = v * ((double)gam[gn]*BNS) + (double)bet[gn];
  v = v > 0.0 ? v : expm1(v);
  out[(size_t)gm*ldo + gn] = v;
}

// ---------------- MFMA bf16 2-split decoder GEMM (elu-bn, two f32 outs) -----
// C = A(f32 [6000][256]) @ Dt(bf16 h/l, [3000][256])^T ; 128x128 tile
__global__ __launch_bounds__(256)
void decomf_k(const float* __restrict__ A,
              const unsigned short* __restrict__ Bh_, const unsigned short* __restrict__ Bl_,
              const float* __restrict__ bias, const float* __restrict__ gam,
              const float* __restrict__ bet,
              float* __restrict__ out1, float* __restrict__ out2)
{
  __shared__ unsigned short lAh[128][40];
  __shared__ unsigned short lAl[128][40];
  __shared__ unsigned short lBh[128][40];
  __shared__ unsigned short lBl[128][40];
  const int tid = threadIdx.x;
  const int n0 = blockIdx.x * 128;
  const int m0 = blockIdx.y * 128;
  const int lane = tid & 63;
  const int wave = tid >> 6;
  const int wm = wave >> 1, wn = wave & 1;
  const int lr = lane & 15;
  const int lk = (lane >> 4) * 8;

  f32x4 acc[4][4];
  #pragma unroll
  for (int i=0;i<4;i++)
    #pragma unroll
    for (int j=0;j<4;j++) acc[i][j] = (f32x4){0.f,0.f,0.f,0.f};

  for (int kt = 0; kt < 8; kt++){
    const int k0 = kt << 5;
    __syncthreads();
    #pragma unroll
    for (int c=0;c<4;c++){
      int lin = tid + c*256;          // 0..1023: 128 rows x 8 chunks of 4
      int row = lin >> 3;
      int kc = (lin & 7) << 2;
      int gm = m0 + row, gn = n0 + row;
      float4 va = make_float4(0.f,0.f,0.f,0.f);
      if (gm < NN) va = *(const float4*)(A + (size_t)gm*256 + k0 + kc);
      ushort4 h, l;
      split2(va.x, h.x, l.x); split2(va.y, h.y, l.y);
      split2(va.z, h.z, l.z); split2(va.w, h.w, l.w);
      *(ushort4*)&lAh[row][kc] = h;
      *(ushort4*)&lAl[row][kc] = l;
      ushort4 bh = {0,0,0,0}, bl = {0,0,0,0};
      if (gn < 3000){
        bh = *(const ushort4*)(Bh_ + (size_t)gn*256 + k0 + kc);
        bl = *(const ushort4*)(Bl_ + (size_t)gn*256 + k0 + kc);
      }
      *(ushort4*)&lBh[row][kc] = bh;
      *(ushort4*)&lBl[row][kc] = bl;
    }
    __syncthreads();
    short8 ah[4], al[4];
    #pragma unroll
    for (int fm=0; fm<4; fm++){
      ah[fm] = *(const short8*)&lAh[wm*64 + fm*16 + lr][lk];
      al[fm] = *(const short8*)&lAl[wm*64 + fm*16 + lr][lk];
    }
    #pragma unroll
    for (int fn=0; fn<4; fn++){
      short8 bh = *(const short8*)&lBh[wn*64 + fn*16 + lr][lk];
      short8 bl = *(const short8*)&lBl[wn*64 + fn*16 + lr][lk];
      #pragma unroll
      for (int fm=0; fm<4; fm++){
        acc[fm][fn] = __builtin_amdgcn_mfma_f32_16x16x32_bf16(ah[fm], bh, acc[fm][fn], 0,0,0);
        acc[fm][fn] = __builtin_amdgcn_mfma_f32_16x16x32_bf16(ah[fm], bl, acc[fm][fn], 0,0,0);
        acc[fm][fn] = __builtin_amdgcn_mfma_f32_16x16x32_bf16(al[fm], bh, acc[fm][fn], 0,0,0);
      }
    }
  }
  const float BNS = 0.99995000374968755f;
  #pragma unroll
  for (int fn=0; fn<4; fn++){
    int gn = n0 + wn*64 + fn*16 + lr;
    if (gn >= 3000) continue;
    float bi = bias[gn];
    float gs = gam[gn]*BNS, be = bet[gn];
    #pragma unroll
    for (int fm=0; fm<4; fm++){
      int gmb = m0 + wm*64 + fm*16 + ((lane >> 4) << 2);
      #pragma unroll
      for (int r=0;r<4;r++){
        int gm = gmb + r;
        if (gm >= NN) continue;
        float v = acc[fm][fn][r] + bi;
        v = v*gs + be; v = v > 0.f ? v : expm1f(v);
        out1[(size_t)gm*3000 + gn] = v;
        out2[(size_t)gm*3000 + gn] = v;
      }
    }
  }
}

// ---------------- CSR build --------------------------------------------------
__global__ void csr_cnt_k(const int* __restrict__ key, int* __restrict__ cnt){
  int e = blockIdx.x*256 + threadIdx.x;
  if (e < NE) atomicAdd(&cnt[key[e]], 1);
}
__global__ __launch_bounds__(256)
void csr_scan_k(const int* __restrict__ cnt, int* __restrict__ rowptr, int* __restrict__ cursor){
  __shared__ int part[256];
  int t = threadIdx.x;
  int base = t*24;
  int loc[24]; int s=0;
  #pragma unroll
  for (int u=0;u<24;u++){
    int idx = base+u;
    int v = (idx<NN) ? cnt[idx] : 0;
    loc[u] = s; s += v;
  }
  part[t] = s;
  __syncthreads();
  if (t==0){
    int run=0;
    for (int u=0;u<256;u++){ int tmp=part[u]; part[u]=run; run+=tmp; }
  }
  __syncthreads();
  int off = part[t];
  #pragma unroll
  for (int u=0;u<24;u++){
    int idx = base+u;
    if (idx<NN){ rowptr[idx]=off+loc[u]; cursor[idx]=off+loc[u]; }
  }
  if (t==255) rowptr[NN] = off + s;
}
__global__ void csr_fill_k(const int* __restrict__ key, int* __restrict__ cursor,
                           int* __restrict__ elist){
  int e = blockIdx.x*256 + threadIdx.x;
  if (e < NE){ int pos = atomicAdd(&cursor[key[e]], 1); elist[pos] = e; }
}

// ---------------- fused per-node attention (dst-CSR, batched 2 encodes) -----
__global__ __launch_bounds__(256)
void attn_k(double* __restrict__ QKVS, const int* __restrict__ rowptr,
            const int* __restrict__ elist, const int* __restrict__ src,
            double* __restrict__ alpha)
{
  __shared__ double lg[4][128];
  const int w = threadIdx.x >> 6;
  const int node = blockIdx.x*4 + w;
  if (node >= 2*NN) return;
  const int base = (node < NN) ? 0 : NN;
  const int aoff = (node < NN) ? 0 : NE;
  const int cn = node - base;
  const int lane = threadIdx.x & 63;
  const int e0 = rowptr[cn], e1 = rowptr[cn+1];
  const int deg = e1 - e0;
  if (deg <= 0) return;
  const double SC = 0.088388347648318447; // 1/sqrt(128)
  const double* q = QKVS + (size_t)node*512;
  double q0 = q[lane], q1 = q[lane+64];

  if (deg <= 128){
    double m = -1.0e300;
    for (int i=0;i<deg;i++){
      const double* k = QKVS + (size_t)(src[elist[e0+i]] + base)*512 + 128;
      double p = q0*k[lane] + q1*k[lane+64];
      #pragma unroll
      for (int off=32; off; off>>=1) p += __shfl_xor(p, off);
      p *= SC;
      if (lane==0) lg[w][i] = p;
      m = fmax(m, p);
    }
    double S = 0.0;
    for (int i=0;i<deg;i++){
      double ex = exp(lg[w][i] - m);
      if (lane==0) lg[w][i] = ex;
      S += ex;
    }
    double inv = 1.0 / S;
    double o0 = QKVS[(size_t)node*512 + 384 + lane];
    double o1 = QKVS[(size_t)node*512 + 448 + lane];
    for (int i=0;i<deg;i++){
      int e = elist[e0+i];
      double a = lg[w][i] * inv;
      const double* v = QKVS + (size_t)(src[e] + base)*512 + 256;
      o0 = fma(a, v[lane],    o0);
      o1 = fma(a, v[lane+64], o1);
      if (lane==0) alpha[aoff + e] = a;
    }
    QKVS[(size_t)node*512 + 384 + lane] = o0;
    QKVS[(size_t)node*512 + 448 + lane] = o1;
  } else {
    double m = -1.0e300;
    for (int i=0;i<deg;i++){
      const double* k = QKVS + (size_t)(src[elist[e0+i]] + base)*512 + 128;
      double p = q0*k[lane] + q1*k[lane+64];
      #pragma unroll
      for (int off=32; off; off>>=1) p += __shfl_xor(p, off);
      m = fmax(m, p*SC);
    }
    double S = 0.0;
    for (int i=0;i<deg;i++){
      const double* k = QKVS + (size_t)(src[elist[e0+i]] + base)*512 + 128;
      double p = q0*k[lane] + q1*k[lane+64];
      #pragma unroll
      for (int off=32; off; off>>=1) p += __shfl_xor(p, off);
      S += exp(p*SC - m);
    }
    double inv = 1.0 / S;
    double o0 = QKVS[(size_t)node*512 + 384 + lane];
    double o1 = QKVS[(size_t)node*512 + 448 + lane];
    for (int i=0;i<deg;i++){
      int e = elist[e0+i];
      const double* k = QKVS + (size_t)(src[e] + base)*512 + 128;
      double p = q0*k[lane] + q1*k[lane+64];
      #pragma unroll
      for (int off=32; off; off>>=1) p += __shfl_xor(p, off);
      double a = exp(p*SC - m) * inv;
      const double* v = QKVS + (size_t)(src[e] + base)*512 + 256;
      o0 = fma(a, v[lane],    o0);
      o1 = fma(a, v[lane+64], o1);
      if (lane==0) alpha[aoff + e] = a;
    }
    QKVS[(size_t)node*512 + 384 + lane] = o0;
    QKVS[(size_t)node*512 + 448 + lane] = o1;
  }
}

// ---------------- fused spmm over src-CSR (both graphs, batched) ------------
__global__ __launch_bounds__(256)
void spmm_csr_k(const double* __restrict__ QK1, const double* __restrict__ QK2,
                const int* __restrict__ rpSA, const int* __restrict__ elSA,
                const int* __restrict__ dstA, const double* __restrict__ aA,
                const int* __restrict__ rpSP, const int* __restrict__ elSP,
                const int* __restrict__ dstP, const double* __restrict__ aP,
                double* __restrict__ out, int ldo, int offo, int dorelu)
{
  const int node = blockIdx.x*4 + (threadIdx.x>>6);
  if (node >= 2*NN) return;
  const int base = (node < NN) ? 0 : NN;
  const int aoff = (node < NN) ? 0 : NE;
  const int cn = node - base;
  const int lane = threadIdx.x & 63;
  double a0 = 0.0, a1 = 0.0;
  for (int idx = rpSA[cn]; idx < rpSA[cn+1]; ++idx){
    int e = elSA[idx]; int d = dstA[e];
    if (d != cn){
      double wgt = 0.5 * aA[aoff + e];
      const double* o = QK1 + (size_t)(d + base)*512 + 384;
      a0 = fma(wgt, o[lane],    a0);
      a1 = fma(wgt, o[lane+64], a1);
    }
  }
  for (int idx = rpSP[cn]; idx < rpSP[cn+1]; ++idx){
    int e = elSP[idx]; int d = dstP[e];
    if (d != cn){
      double wgt = 0.5 * aP[aoff + e];
      const double* o = QK2 + (size_t)(d + base)*512 + 384;
      a0 = fma(wgt, o[lane],    a0);
      a1 = fma(wgt, o[lane+64], a1);
    }
  }
  if (dorelu){ a0 = fmax(a0, 0.0); a1 = fmax(a1, 0.0); }
  out[(size_t)node*ldo + offo + lane]      = a0;
  out[(size_t)node*ldo + offo + 64 + lane] = a1;
}

__global__ void att_scatter_k(const int* __restrict__ src, const int* __restrict__ dst,
                              const double* __restrict__ alpha, float* __restrict__ att)
{
  int e = blockIdx.x*256 + threadIdx.x;
  if (e >= NE) return;
  int s = src[e], d = dst[e];
  if (s == d) return;
  atomicAdd(&att[(size_t)s*NN + d], (float)alpha[e]);
}

// ---------------- MFMA bf16 2-split distance + fused per-tile top-12 --------
__global__ __launch_bounds__(256)
void distmf_k(const unsigned short* __restrict__ zXh, const unsigned short* __restrict__ zXl,
              const unsigned short* __restrict__ zNh, const unsigned short* __restrict__ zNl,
              const float* __restrict__ sxA, const float* __restrict__ syA,
              const float* __restrict__ cjA,
              float* __restrict__ candV, int* __restrict__ candI)
{
  __shared__ __align__(16) char smem[40960 + 1536];
  typedef unsigned short u16;
  u16 (*lAh)[40] = (u16(*)[40])(smem);
  u16 (*lAl)[40] = (u16(*)[40])(smem + 10240);
  u16 (*lBh)[40] = (u16(*)[40])(smem + 20480);
  u16 (*lBl)[40] = (u16(*)[40])(smem + 30720);
  float (*stile)[67] = (float(*)[67])(smem);     // overlay after K loop
  float* sSx = (float*)(smem + 40960);
  float* sSy = sSx + 128;
  float* sC  = sSy + 128;

  const int tid = threadIdx.x;
  const int m0 = blockIdx.y * 128;
  const int n0 = blockIdx.x * 128;
  const int lane = tid & 63;
  const int wave = tid >> 6;
  const int wm = wave >> 1, wn = wave & 1;
  const int lr = lane & 15;
  const int lk = (lane >> 4) * 8;

  if (tid < 128){
    int jg = n0 + tid;
    if (jg < NN){ sSx[tid]=sxA[jg]; sSy[tid]=syA[jg]; sC[tid]=cjA[jg]; }
    else        { sSx[tid]=0.f; sSy[tid]=0.f; sC[tid]=-3e38f; }
  }

  f32x4 acc[4][4];
  #pragma unroll
  for (int i=0;i<4;i++)
    #pragma unroll
    for (int j=0;j<4;j++) acc[i][j] = (f32x4){0.f,0.f,0.f,0.f};

  for (int kt = 0; kt < 8; kt++){
    const int k0 = kt << 5;
    __syncthreads();
    #pragma unroll
    for (int c=0;c<4;c++){
      int lin = tid + c*256;
      int row = lin >> 3;
      int kc = (lin & 7) << 2;
      int gm = m0 + row, gn = n0 + row;
      ushort4 vh = {0,0,0,0}, vl = {0,0,0,0}, wh = {0,0,0,0}, wl = {0,0,0,0};
      if (gm < NN){
        vh = *(const ushort4*)(zXh + (size_t)gm*256 + k0 + kc);
        vl = *(const ushort4*)(zXl + (size_t)gm*256 + k0 + kc);
      }
      if (gn < NN){
        wh = *(const ushort4*)(zNh + (size_t)gn*256 + k0 + kc);
        wl = *(const ushort4*)(zNl + (size_t)gn*256 + k0 + kc);
      }
      *(ushort4*)&lAh[row][kc] = vh;
      *(ushort4*)&lAl[row][kc] = vl;
      *(ushort4*)&lBh[row][kc] = wh;
      *(ushort4*)&lBl[row][kc] = wl;
    }
    __syncthreads();
    short8 ah[4], al[4];
    #pragma unroll
    for (int fm=0; fm<4; fm++){
      ah[fm] = *(const short8*)&lAh[wm*64 + fm*16 + lr][lk];
      al[fm] = *(const short8*)&lAl[wm*64 + fm*16 + lr][lk];
    }
    #pragma unroll
    for (int fn=0; fn<4; fn++){
      short8 bh = *(const short8*)&lBh[wn*64 + fn*16 + lr][lk];
      short8 bl = *(const short8*)&lBl[wn*64 + fn*16 + lr][lk];
      #pragma unroll
      for (int fm=0; fm<4; fm++){
        acc[fm][fn] = __builtin_amdgcn_mfma_f32_16x16x32_bf16(ah[fm], bh, acc[fm][fn], 0,0,0);
        acc[fm][fn] = __builtin_amdgcn_mfma_f32_16x16x32_bf16(ah[fm], bl, acc[fm][fn], 0,0,0);
        acc[fm][fn] = __builtin_amdgcn_mfma_f32_16x16x32_bf16(al[fm], bh, acc[fm][fn], 0,0,0);
      }
    }
  }

  float tv[NCAND]; int ti[NCAND];
  #pragma unroll
  for (int p=0;p<NCAND;p++){ tv[p] = -3.4e38f; ti[p] = -1; }
  const int gi = m0 + tid;
  float sxi = 0.f, syi = 0.f;
  if (tid < 128 && gi < NN){ sxi = sxA[gi]; syi = syA[gi]; }

  for (int jh = 0; jh < 2; jh++){
    __syncthreads();
    if (wn == jh){
      #pragma unroll
      for (int fm=0;fm<4;fm++){
        #pragma unroll
        for (int fn=0;fn<4;fn++){
          int lrow = wm*64 + fm*16 + ((lane>>4)<<2);
          int lcol = fn*16 + lr;
          #pragma unroll
          for (int r=0;r<4;r++)
            stile[lrow + r][lcol] = acc[fm][fn][r];
        }
      }
    }
    __syncthreads();
    if (tid < 128 && gi < NN){
      #pragma unroll 1
      for (int jj=0; jj<64; jj++){
        int j = jh*64 + jj;
        float s = 2.f*stile[tid][jj] + 2.f*(sxi*sSx[j] + syi*sSy[j]) + sC[j];
        if (s > tv[NCAND-1]){
          bool g[NCAND];
          #pragma unroll
          for (int p=0;p<NCAND;p++) g[p] = s > tv[p];
          #pragma unroll
          for (int p=NCAND-1;p>0;--p) if (g[p-1]){ tv[p]=tv[p-1]; ti[p]=ti[p-1]; }
          #pragma unroll
          for (int p=0;p<NCAND;p++){ bool pl = g[p] && (p==0 || !g[p-1]); if (pl){ tv[p]=s; ti[p]=n0+j; } }
        }
      }
    }
  }
  if (tid < 128 && gi < NN){
    size_t base = ((size_t)gi*NTILE + blockIdx.x)*NCAND;
    #pragma unroll
    for (int p=0;p<NCAND;p++){ candV[base+p]=tv[p]; candI[base+p]=ti[p]; }
  }
}

// ---------------- merge: 32x block-argmax prefilter -> f64 rescore -> top-9 -
__global__ __launch_bounds__(256)
void merge64_k(const float* __restrict__ candV, const int* __restrict__ candI,
               const double* __restrict__ Z, const double* __restrict__ Znb,
               const double* __restrict__ sx64, const double* __restrict__ sy64,
               double* __restrict__ wgt9, int* __restrict__ idx9)
{
  __shared__ double zi[256];
  __shared__ int    fjS[TCAND];
  __shared__ float  wbv[4];
  __shared__ int    wbc[4];
  __shared__ int    chosen;
  __shared__ int    pj[PRE];
  __shared__ double ps[PRE];

  const int i = blockIdx.x;
  const int t = threadIdx.x;
  const int lane = t & 63, wv = t >> 6;

  zi[t] = Z[(size_t)i*256 + t];

  float v0 = -3.4e38f, v1 = -3.4e38f, v2 = -3.4e38f;
  const int c0 = t, c1 = t + 256, c2 = t + 512;
  {
    float vv = candV[(size_t)i*TCAND + c0];
    int jj = candI[(size_t)i*TCAND + c0];
    fjS[c0] = jj;
    if (jj >= 0) v0 = vv;
  }
  if (c1 < TCAND){
    float vv = candV[(size_t)i*TCAND + c1];
    int jj = candI[(size_t)i*TCAND + c1];
    fjS[c1] = jj;
    if (jj >= 0) v1 = vv;
  }
  if (c2 < TCAND){
    float vv = candV[(size_t)i*TCAND + c2];
    int jj = candI[(size_t)i*TCAND + c2];
    fjS[c2] = jj;
    if (jj >= 0) v2 = vv;
  }
  __syncthreads();

  for (int it = 0; it < PRE; it++){
    float bv = v0; int bc = c0;
    if (v1 > bv || (v1 == bv && c1 < bc)){ bv = v1; bc = c1; }
    if (v2 > bv || (v2 == bv && c2 < bc)){ bv = v2; bc = c2; }
    #pragma unroll
    for (int off = 32; off; off >>= 1){
      float ov = __shfl_xor(bv, off);
      int   oc = __shfl_xor(bc, off);
      if (ov > bv || (ov == bv && oc < bc)){ bv = ov; bc = oc; }
    }
    if (lane == 0){ wbv[wv] = bv; wbc[wv] = bc; }
    __syncthreads();
    if (t == 0){
      float gb = wbv[0]; int gc = wbc[0];
      #pragma unroll
      for (int w2 = 1; w2 < 4; w2++)
        if (wbv[w2] > gb || (wbv[w2] == gb && wbc[w2] < gc)){ gb = wbv[w2]; gc = wbc[w2]; }
      chosen = gc;
      pj[it] = fjS[gc];
    }
    __syncthreads();
    int gc = chosen;
    if (c0 == gc) v0 = -3.4e38f;
    if (c1 == gc) v1 = -3.4e38f;
    if (c2 == gc) v2 = -3.4e38f;
  }

  const double sxi = sx64[i], syi = sy64[i];
  for (int c = wv; c < PRE; c += 4){
    int j = pj[c];
    const double* zj = Znb + (size_t)j*256;
    double p = 0.0;
    #pragma unroll
    for (int u = 0; u < 4; u++){
      double b = zj[lane + 64*u];
      double a = zi[lane + 64*u];
      p = fma(2.0*a - b, b, p);     // += 2ab - b^2
    }
    #pragma unroll
    for (int off = 32; off; off >>= 1) p += __shfl_xor(p, off);
    double sxj = sx64[j], syj = sy64[j];
    double s = p + 2.0*(sxi*sxj + syi*syj) - (sxj*sxj + syj*syj);
    if (lane == 0) ps[c] = s;
  }
  __syncthreads();

  if (t == 0){
    double tv9[9]; int ti9[9];
    #pragma unroll
    for (int p = 0; p < 9; p++){ tv9[p] = -1.0e301; ti9[p] = 0x7FFFFFFF; }
    for (int c = 0; c < PRE; c++){
      double s = ps[c]; int j = pj[c];
      if (!((s > tv9[8]) || (s == tv9[8] && j < ti9[8]))) continue;
      int p = 8;
      while (p > 0 && ((s > tv9[p-1]) || (s == tv9[p-1] && j < ti9[p-1]))){
        tv9[p] = tv9[p-1]; ti9[p] = ti9[p-1]; --p;
      }
      tv9[p] = s; ti9[p] = j;
    }
    double m = tv9[0], e[9], S = 0.0;
    #pragma unroll
    for (int k = 0; k < 9; k++){ e[k] = exp(tv9[k] - m); S += e[k]; }
    #pragma unroll
    for (int k = 0; k < 9; k++){
      wgt9[(size_t)i*9 + k] = e[k] / S;
      idx9[(size_t)i*9 + k] = ti9[k];
    }
  }
}

// ---------------- znb prep + casts ------------------------------------------
__global__ __launch_bounds__(256)
void znbprep_k(const double* __restrict__ znb, const double* __restrict__ ssq64,
               float* __restrict__ cjA)
{
  __shared__ double red[256];
  int i = blockIdx.x, d = threadIdx.x;
  double v = znb[(size_t)i*256 + d];
  red[d] = v*v;
  __syncthreads();
  for (int s=128; s; s>>=1){ if (d<s) red[d]+=red[d+s]; __syncthreads(); }
  if (d==0) cjA[i] = -(float)(red[0] + ssq64[i]);
}
__global__ void featout_k(const double* __restrict__ z, float* __restrict__ o){
  int t = blockIdx.x*256+threadIdx.x;
  if (t < NN*128){ int i=t>>7, d=t&127; o[t] = (float)z[(size_t)i*256 + d]; }
}

__global__ __launch_bounds__(256)
void zout_k(const double* __restrict__ Z, const double* __restrict__ Znb,
            const int* __restrict__ idx9, const double* __restrict__ wgt9,
            float* __restrict__ zoOut, float* __restrict__ zoF32, float* __restrict__ x1)
{
  int i = blockIdx.x; int d = threadIdx.x;
  double a = Z[(size_t)i*256 + d];
  #pragma unroll
  for (int k=0;k<9;k++){
    int j = idx9[(size_t)i*9+k];
    double w = wgt9[(size_t)i*9+k];
    double t = w * Znb[(size_t)j*256 + d];
    a += t;
    x1[((size_t)i*9+k)*256 + d] = (float)t;
  }
  float af = (float)a;
  zoOut[(size_t)i*256+d] = af;
  zoF32[(size_t)i*256+d] = af;
}

__global__ __launch_bounds__(256)
void q_k(const float* __restrict__ zoF, const float* __restrict__ clus, float* __restrict__ qB)
{
  __shared__ float wred[10][4];
  __shared__ float qs[10];
  int i = blockIdx.x, d = threadIdx.x;
  int lane = d & 63, wv = d >> 6;
  float zo = zoF[(size_t)i*256 + d];
  #pragma unroll
  for (int c=0;c<10;c++){
    float df = zo - clus[(size_t)c*256 + d];
    float p = df*df;
    #pragma unroll
    for (int off=32; off; off>>=1) p += __shfl_down(p, off);
    if (lane == 0) wred[c][wv] = p;
  }
  __syncthreads();
  if (d < 10){
    float d2 = wred[d][0]+wred[d][1]+wred[d][2]+wred[d][3];
    qs[d] = 1.f/(1.f + d2);
  }
  __syncthreads();
  if (d < 10){
    float s = 0.f;
    #pragma unroll
    for (int c=0;c<10;c++) s += qs[c];
    qB[(size_t)i*10 + d] = qs[d]/s;
  }
}

// ---------------- host ------------------------------------------------------
extern "C" void kernel_launch(void* const* d_in, const int* in_sizes, int n_in,
                              void* d_out, int out_size, void* d_ws, size_t ws_size,
                              hipStream_t stream)
{
  (void)in_sizes; (void)n_in; (void)out_size; (void)ws_size;
  const float* x    = (const float*)d_in[0];
  const float* xnb  = (const float*)d_in[1];
  const float* spat = (const float*)d_in[2];
  const int*   adj  = (const int*)d_in[3];
  const int*   adjp = (const int*)d_in[4];
  const float* W1   = (const float*)d_in[5];
  const float* b1   = (const float*)d_in[6];
  const float* g1   = (const float*)d_in[7];
  const float* be1  = (const float*)d_in[8];
  const float* W2   = (const float*)d_in[9];
  const float* b2   = (const float*)d_in[10];
  const float* g2   = (const float*)d_in[11];
  const float* be2  = (const float*)d_in[12];
  const float* Wq   = (const float*)d_in[13];
  const float* Wk   = (const float*)d_in[14];
  const float* Wv   = (const float*)d_in[15];
  const float* Wsm  = (const float*)d_in[16];
  const float* bq   = (const float*)d_in[17];
  const float* bk   = (const float*)d_in[18];
  const float* bv   = (const float*)d_in[19];
  const float* bs   = (const float*)d_in[20];
  const float* decW = (const float*)d_in[21];
  const float* decb = (const float*)d_in[22];
  const float* decg = (const float*)d_in[23];
  const float* decbe= (const float*)d_in[24];
  const float* clus = (const float*)d_in[25];
  float* outF = (float*)d_out;
  const int* srcA = adj,  *dstA = adj + NE;
  const int* srcP = adjp, *dstP = adjp + NE;

  char* wsb = (char*)d_ws;
  size_t off = 0;
  auto alloc = [&](size_t bytes)->char*{
    char* p = wsb + off;
    off = (off + bytes + 255) & ~(size_t)255;
    return p;
  };
  double* W1t  = (double*)alloc(768000*8);
  double* W2t  = (double*)alloc(32768*8);
  double* Bct  = (double*)alloc(196608*8);
  unsigned short* DtH = (unsigned short*)alloc(768000*2);
  unsigned short* DtL = (unsigned short*)alloc(768000*2);
  double* bcat = (double*)alloc(1536*8);
  double* sx64 = (double*)alloc(NN*8);
  double* sy64 = (double*)alloc(NN*8);
  double* ssq64= (double*)alloc(NN*8);
  float*  sx32 = (float*) alloc(NN*4);
  float*  sy32 = (float*) alloc(NN*4);
  double* b1c  = (double*)alloc(256*8);
  double* b2c  = (double*)alloc(128*8);
  double* H1   = (double*)alloc((size_t)2*NN*256*8);
  double* zAll = (double*)alloc((size_t)2*NN*256*8);
  double* hcur = (double*)alloc((size_t)2*NN*128*8);
  double* QK1  = (double*)alloc((size_t)2*NN*512*8);
  double* QK2  = (double*)alloc((size_t)2*NN*512*8);
  double* alphaA=(double*)alloc((size_t)2*NE*8);
  double* alphaP=(double*)alloc((size_t)2*NE*8);
  double* part = (double*)alloc((size_t)4*2*NN*256*8);   // split-K partials (98 MB)
  // CSRs
  int* rpDA = (int*)alloc((NN+1)*4);
  int* rpDP = (int*)alloc((NN+1)*4);
  int* rpSA = (int*)alloc((NN+1)*4);
  int* rpSP = (int*)alloc((NN+1)*4);
  int* curDA= (int*)alloc(NN*4);
  int* curDP= (int*)alloc(NN*4);
  int* curSA= (int*)alloc(NN*4);
  int* curSP= (int*)alloc(NN*4);
  int* elDA = (int*)alloc(NE*4);
  int* elDP = (int*)alloc(NE*4);
  int* elSA = (int*)alloc(NE*4);
  int* elSP = (int*)alloc(NE*4);
  unsigned short* zXh = (unsigned short*)alloc((size_t)NN*256*2);
  unsigned short* zXl = (unsigned short*)alloc((size_t)NN*256*2);
  unsigned short* zNh = (unsigned short*)alloc((size_t)NN*256*2);
  unsigned short* zNl = (unsigned short*)alloc((size_t)NN*256*2);
  float*  cjA  = (float*) alloc(NN*4);
  float*  candV= (float*) alloc((size_t)NN*TCAND*4);
  int*    candI= (int*)   alloc((size_t)NN*TCAND*4);
  int*    idx9 = (int*)   alloc((size_t)NN*9*4);
  double* wgt9 = (double*)alloc((size_t)NN*9*8);
  float*  zoF32= (float*) alloc((size_t)NN*256*4);

  double* zX64  = zAll;
  double* zNB64 = zAll + (size_t)NN*256;

  prep_k<<<6926, 256, 0, stream>>>(W1, W2, Wq, Wk, Wv, Wsm, bq, bk, bv, bs, decW, spat,
                                   W1t, W2t, Bct, DtH, DtL, bcat,
                                   sx64, sy64, ssq64, sx32, sy32);
  castup_k<<<1, 256, 0, stream>>>(b1, b1c, 256);
  castup_k<<<1, 256, 0, stream>>>(b2, b2c, 128);

  // CSR build (4 CSRs)
  hipMemsetAsync(curDA, 0, NN*4, stream);
  hipMemsetAsync(curDP, 0, NN*4, stream);
  hipMemsetAsync(curSA, 0, NN*4, stream);
  hipMemsetAsync(curSP, 0, NN*4, stream);
  csr_cnt_k<<<375, 256, 0, stream>>>(dstA, curDA);
  csr_cnt_k<<<375, 256, 0, stream>>>(dstP, curDP);
  csr_cnt_k<<<375, 256, 0, stream>>>(srcA, curSA);
  csr_cnt_k<<<375, 256, 0, stream>>>(srcP, curSP);
  csr_scan_k<<<1, 256, 0, stream>>>(curDA, rpDA, curDA);
  csr_scan_k<<<1, 256, 0, stream>>>(curDP, rpDP, curDP);
  csr_scan_k<<<1, 256, 0, stream>>>(curSA, rpSA, curSA);
  csr_scan_k<<<1, 256, 0, stream>>>(curSP, rpSP, curSP);
  csr_fill_k<<<375, 256, 0, stream>>>(dstA, curDA, elDA);
  csr_fill_k<<<375, 256, 0, stream>>>(dstP, curDP, elDP);
  csr_fill_k<<<375, 256, 0, stream>>>(srcA, curSA, elSA);
  csr_fill_k<<<375, 256, 0, stream>>>(srcP, curSP, elSP);

  const int M2 = 2*NN;   // 12000 batched rows

  // batched encoder GEMM 1: A rows [0,6000) from x, [6000,12000) from xnb
  gemm64s_k<float><<<dim3(4,188,4), 256, 0, stream>>>(x, xnb, NN, KDIN, W1t, KDIN,
                                                      M2, KDIN, 768, 256, part);
  epi64_k<<<(M2*256+255)/256, 256, 0, stream>>>(part, 4, (size_t)M2*256,
                                                M2, 256, b1c, g1, be1, H1, 256);
  // batched encoder GEMM 2
  gemm64s_k<double><<<dim3(2,188,4), 256, 0, stream>>>(H1, H1, M2, 256, W2t, 256,
                                                       M2, 256, 64, 128, part);
  epi64_k<<<(M2*128+255)/256, 256, 0, stream>>>(part, 4, (size_t)M2*128,
                                                M2, 128, b2c, g2, be2, zAll, 256);

  const double* hin = zAll; int ldh = 256;
  for (int l=0; l<3; l++){
    const double* Bh = Bct + (size_t)l*65536;
    const double* bc = bcat + l*512;
    if (l != 1){
      gemm64_k<0,double><<<dim3(8,188), 256, 0, stream>>>(hin, ldh, Bh, 128, M2, 128, 512,
                                                          QK1, 512, bc, nullptr, nullptr, QK2);
      attn_k<<<3000, 256, 0, stream>>>(QK1, rpDA, elDA, srcA, alphaA);
      attn_k<<<3000, 256, 0, stream>>>(QK2, rpDP, elDP, srcP, alphaP);
    } else {
      gemm64_k<0,double><<<dim3(8,188), 256, 0, stream>>>(hin, ldh, Bh, 128, M2, 128, 512,
                                                          QK1, 512, bc, nullptr, nullptr, nullptr);
      attn_k<<<3000, 256, 0, stream>>>(QK1, rpDA, elDA, srcA, alphaA);
      gemm64_k<0,double><<<dim3(8,188), 256, 0, stream>>>(QK1 + 384, 512, Bh, 128, M2, 128, 512,
                                                          QK2, 512, bc, nullptr, nullptr, nullptr);
      attn_k<<<3000, 256, 0, stream>>>(QK2, rpDP, elDP, srcP, alphaP);
    }
    if (l == 2){
      hipMemsetAsync(outF + (size_t)OFF_ATT, 0, (size_t)NN*NN*4, stream);
      att_scatter_k<<<375, 256, 0, stream>>>(srcP, dstP, alphaP, outF + (size_t)OFF_ATT);
    }
    if (l < 2){
      spmm_csr_k<<<3000, 256, 0, stream>>>(QK1, QK2, rpSA, elSA, dstA, alphaA,
                                           rpSP, elSP, dstP, alphaP, hcur, 128, 0, 1);
      hin = hcur; ldh = 128;
    } else {
      spmm_csr_k<<<3000, 256, 0, stream>>>(QK1, QK2, rpSA, elSA, dstA, alphaA,
                                           rpSP, elSP, dstP, alphaP, zAll, 256, 128, 0);
    }
  }

  splitz_k<<<6000, 256, 0, stream>>>(zX64,  zXh, zXl, NN*256);
  splitz_k<<<6000, 256, 0, stream>>>(zNB64, zNh, zNl, NN*256);
  znbprep_k<<<NN, 256, 0, stream>>>(zNB64, ssq64, cjA);
  distmf_k<<<dim3(NTILE,47), 256, 0, stream>>>(zXh, zXl, zNh, zNl,
                                               sx32, sy32, cjA, candV, candI);
  merge64_k<<<NN, 256, 0, stream>>>(candV, candI, zX64, zNB64, sx64, sy64, wgt9, idx9);

  zout_k<<<NN, 256, 0, stream>>>(zX64, zNB64, idx9, wgt9,
                                 outF + (size_t)OFF_ZOUT, zoF32, outF + (size_t)OFF_X1);
  decomf_k<<<dim3(24,47), 256, 0, stream>>>(zoF32, DtH, DtL, decb, decg, decbe,
                                            outF + (size_t)OFF_DE1, outF + (size_t)OFF_DE2);
  q_k<<<NN, 256, 0, stream>>>(zoF32, clus, outF + (size_t)OFF_Q);
  featout_k<<<3000, 256, 0, stream>>>(zX64, outF + (size_t)OFF_FEAT);
}